// Round 13
// baseline (211.211 us; speedup 1.0000x reference)
//
#include <hip/hip_runtime.h>
#include <hip/hip_fp16.h>

#define N_NODES 50000
#define E_EDGES 800000
#define SCAN_TILE 1024
#define SCAN_NBLK ((N_NODES + SCAN_TILE - 1) / SCAN_TILE)   // 49
#define EW_EPT 4    // edges per octet per wave-iteration

__device__ __forceinline__ float sgpr_f(float x) {
    return __uint_as_float(__builtin_amdgcn_readfirstlane(__float_as_uint(x)));
}

#if defined(__has_builtin)
#if __has_builtin(__builtin_amdgcn_fdot2)
#define HAS_FDOT2 1
#endif
#endif

typedef _Float16 v2h_t __attribute__((ext_vector_type(2)));

__device__ __forceinline__ float fdot2f(__half2 a, __half2 b, float c) {
#ifdef HAS_FDOT2
    return __builtin_amdgcn_fdot2(*reinterpret_cast<v2h_t*>(&a),
                                  *reinterpret_cast<v2h_t*>(&b), c, false);
#else
    const float2 fa = __half22float2(a);
    const float2 fb = __half22float2(b);
    return fmaf(fa.x, fb.x, fmaf(fa.y, fb.y, c));
#endif
}

// packed relu: v_pk_max_f16 with inline constant 0
__device__ __forceinline__ __half2 relu_h2(__half2 x) {
    union { __half2 h; unsigned u; } a, r;
    a.h = x;
    asm("v_pk_max_f16 %0, %1, 0" : "=v"(r.u) : "v"(a.u));
    return r.h;
}

// DPP cross-lane moves (VALU pipe, no LDS).
// 0xB1 = quad_perm lane^1, 0x4E = quad_perm lane^2,
// 0x141 = ROW_HALF_MIRROR (lane i <-> 7-i within aligned 8-lane groups).
template <int CTRL>
__device__ __forceinline__ float dpp_mov_f32(float x) {
    return __int_as_float(__builtin_amdgcn_update_dpp(
        0, __float_as_int(x), CTRL, 0xF, 0xF, true));
}
// full 8-lane (octet) all-reduce (validated r11)
__device__ __forceinline__ float oct_sum(float x) {
    x += dpp_mov_f32<0xB1>(x);
    x += dpp_mov_f32<0x4E>(x);
    x += dpp_mov_f32<0x141>(x);
    return x;
}
__device__ __forceinline__ float oct_max(float x) {
    x = fmaxf(x, dpp_mov_f32<0xB1>(x));
    x = fmaxf(x, dpp_mov_f32<0x4E>(x));
    x = fmaxf(x, dpp_mov_f32<0x141>(x));
    return x;
}

// ---------------------------------------------------------------------------
// Projection kernel, LDS-free: W rows are read at identical addresses by all
// 16 column-groups -> L1 broadcast. 32 rows/block (grid 1563 = 6 blocks/CU),
// 2 rows/thread x 4 cols. Also zeroes cnt[] (replaces the memset dispatch).
// ---------------------------------------------------------------------------
__global__ __launch_bounds__(256) void proj_kernel(
    const float* __restrict__ qin, const float* __restrict__ kin, const float* __restrict__ vin,
    const float* __restrict__ Wq, const float* __restrict__ bq,
    const float* __restrict__ Wk, const float* __restrict__ bk,
    const float* __restrict__ Wv, const float* __restrict__ bv,
    __half* __restrict__ xq, __half* __restrict__ xk, __half* __restrict__ xv,
    int* __restrict__ cnt)
{
    const int tid = threadIdx.x;

    // zero the histogram buffer (runs before edge_weights' atomics)
    const int gid = blockIdx.x * 256 + tid;
    if (gid < N_NODES) cnt[gid] = 0;

    const int cg = tid & 15;   // column group (4 cols)
    const int rg = tid >> 4;   // row slot (0..15)
    const int c0 = cg * 4;
    const int base = blockIdx.x * 32;

    int rowA = base + rg;
    int rowB = base + 16 + rg;
    const bool okA = rowA < N_NODES;
    const bool okB = rowB < N_NODES;
    if (!okA) rowA = N_NODES - 1;
    if (!okB) rowB = N_NODES - 1;

    const float* ins[3]  = {qin, kin, vin};
    const float* Wms[3]  = {Wq, Wk, Wv};
    const float* bs[3]   = {bq, bk, bv};
    __half*      outs[3] = {xq, xk, xv};

    #pragma unroll
    for (int m = 0; m < 3; ++m) {
        const float* in = ins[m];
        const float* Wm = Wms[m];
        const float4 b4 = *reinterpret_cast<const float4*>(&bs[m][c0]);
        float4 accA = b4, accB = b4;

        for (int kk = 0; kk < 64; kk += 4) {
            const float4 ra = *reinterpret_cast<const float4*>(&in[rowA * 64 + kk]);
            const float4 rb = *reinterpret_cast<const float4*>(&in[rowB * 64 + kk]);
            #pragma unroll
            for (int dk = 0; dk < 4; ++dk) {
                const float4 w4 = *reinterpret_cast<const float4*>(&Wm[(kk + dk) * 64 + c0]);
                const float xa = reinterpret_cast<const float*>(&ra)[dk];
                const float xb = reinterpret_cast<const float*>(&rb)[dk];
                accA.x = fmaf(xa, w4.x, accA.x);
                accA.y = fmaf(xa, w4.y, accA.y);
                accA.z = fmaf(xa, w4.z, accA.z);
                accA.w = fmaf(xa, w4.w, accA.w);
                accB.x = fmaf(xb, w4.x, accB.x);
                accB.y = fmaf(xb, w4.y, accB.y);
                accB.z = fmaf(xb, w4.z, accB.z);
                accB.w = fmaf(xb, w4.w, accB.w);
            }
        }
        if (okA) {
            union { __half2 h[2]; uint2 u; } pk;
            pk.h[0] = __floats2half2_rn(accA.x, accA.y);
            pk.h[1] = __floats2half2_rn(accA.z, accA.w);
            *reinterpret_cast<uint2*>(&outs[m][(size_t)rowA * 64 + c0]) = pk.u;
        }
        if (okB) {
            union { __half2 h[2]; uint2 u; } pk;
            pk.h[0] = __floats2half2_rn(accB.x, accB.y);
            pk.h[1] = __floats2half2_rn(accB.z, accB.w);
            *reinterpret_cast<uint2*>(&outs[m][(size_t)rowB * 64 + c0]) = pk.u;
        }
    }
}

// ---------------------------------------------------------------------------
// Hierarchical scan, step A: per-1024-element block sums (49 blocks).
// ---------------------------------------------------------------------------
__global__ __launch_bounds__(256) void scan_sums(
    const int* __restrict__ cnt, int* __restrict__ bsum)
{
    const int tid  = threadIdx.x;
    const int base = blockIdx.x * SCAN_TILE + tid * 4;
    int s = 0;
    if (base + 3 < N_NODES) {
        const int4 t = *reinterpret_cast<const int4*>(&cnt[base]);
        s = t.x + t.y + t.z + t.w;
    } else {
        #pragma unroll
        for (int i = 0; i < 4; ++i)
            if (base + i < N_NODES) s += cnt[base + i];
    }
    #pragma unroll
    for (int d = 1; d < 64; d <<= 1) s += __shfl_xor(s, d);
    __shared__ int ws[4];
    if ((tid & 63) == 0) ws[tid >> 6] = s;
    __syncthreads();
    if (tid == 0) bsum[blockIdx.x] = ws[0] + ws[1] + ws[2] + ws[3];
}

// ---------------------------------------------------------------------------
// Hierarchical scan, step B+C fused: wave 0 redundantly exclusive-scans the
// 49 block sums (replaces the scan_bsum dispatch), then the block does its
// local exclusive scan + offset. Writes off[] and re-purposes cnt[] as the
// scatter cursor.
// ---------------------------------------------------------------------------
__global__ __launch_bounds__(256) void scan_final(
    int* __restrict__ cnt, const int* __restrict__ bsum, int* __restrict__ off)
{
    __shared__ int s_boff;
    __shared__ int wsum[4];
    const int tid  = threadIdx.x;
    const int base = blockIdx.x * SCAN_TILE + tid * 4;

    // wave 0: exclusive prefix of bsum, pick this block's offset
    if (tid < 64) {
        const int v = (tid < SCAN_NBLK) ? bsum[tid] : 0;
        int bincl = v;
        #pragma unroll
        for (int d = 1; d < 64; d <<= 1) {
            const int t = __shfl_up(bincl, d);
            if (tid >= d) bincl += t;
        }
        if (tid == blockIdx.x) s_boff = bincl - v;
    }

    int v0 = 0, v1 = 0, v2 = 0, v3 = 0;
    if (base + 3 < N_NODES) {
        const int4 t = *reinterpret_cast<const int4*>(&cnt[base]);
        v0 = t.x; v1 = t.y; v2 = t.z; v3 = t.w;
    } else {
        if (base + 0 < N_NODES) v0 = cnt[base + 0];
        if (base + 1 < N_NODES) v1 = cnt[base + 1];
        if (base + 2 < N_NODES) v2 = cnt[base + 2];
        if (base + 3 < N_NODES) v3 = cnt[base + 3];
    }
    const int s = v0 + v1 + v2 + v3;

    int incl = s;
    #pragma unroll
    for (int d = 1; d < 64; d <<= 1) {
        const int t = __shfl_up(incl, d);
        if ((tid & 63) >= d) incl += t;
    }
    const int wave = tid >> 6;
    if ((tid & 63) == 63) wsum[wave] = incl;
    __syncthreads();
    int woff = 0;
    #pragma unroll
    for (int w = 0; w < 3; ++w)
        if (w < wave) woff += wsum[w];

    int run = s_boff + woff + (incl - s);
    if (base + 0 < N_NODES) { off[base + 0] = run; cnt[base + 0] = run; run += v0; }
    if (base + 1 < N_NODES) { off[base + 1] = run; cnt[base + 1] = run; run += v1; }
    if (base + 2 < N_NODES) { off[base + 2] = run; cnt[base + 2] = run; run += v2; }
    if (base + 3 < N_NODES) { off[base + 3] = run; cnt[base + 3] = run; run += v3; }

    if (blockIdx.x == 0 && tid == 0) off[N_NODES] = E_EDGES;
}

// ---------------------------------------------------------------------------
// Edge-weights kernel (r11-proven): octet-per-edge, all cross-lane ops via
// DPP. Lane r owns channels 8r..8r+7. W1 slice = 32 VGPRs (half2-packed).
// Coalesced edge-order outputs + degree histogram.
// ---------------------------------------------------------------------------
__global__ __launch_bounds__(256) void edge_weights(
    const int* __restrict__ eidx, const float* __restrict__ edges,
    const float* __restrict__ Wp, const float* __restrict__ bp,
    const float* __restrict__ W1, const float* __restrict__ b1,
    const float* __restrict__ W2, const float* __restrict__ b2,
    const __half* __restrict__ xq, const __half* __restrict__ xk,
    int* __restrict__ cnt, float2* __restrict__ ep2e, ushort* __restrict__ wout16)
{
    const int tid  = threadIdx.x;
    const int lane = tid & 63;
    const int o    = lane >> 3;
    const int r    = lane & 7;
    const int wave = tid >> 6;

    __half2 W1h[4][8];
    #pragma unroll
    for (int i = 0; i < 4; ++i) {
        const float4 a0 = *reinterpret_cast<const float4*>(&W1[(8 * r + 2 * i) * 8]);
        const float4 a1 = *reinterpret_cast<const float4*>(&W1[(8 * r + 2 * i) * 8 + 4]);
        const float4 c0 = *reinterpret_cast<const float4*>(&W1[(8 * r + 2 * i + 1) * 8]);
        const float4 c1 = *reinterpret_cast<const float4*>(&W1[(8 * r + 2 * i + 1) * 8 + 4]);
        W1h[i][0] = __floats2half2_rn(a0.x, c0.x);
        W1h[i][1] = __floats2half2_rn(a0.y, c0.y);
        W1h[i][2] = __floats2half2_rn(a0.z, c0.z);
        W1h[i][3] = __floats2half2_rn(a0.w, c0.w);
        W1h[i][4] = __floats2half2_rn(a1.x, c1.x);
        W1h[i][5] = __floats2half2_rn(a1.y, c1.y);
        W1h[i][6] = __floats2half2_rn(a1.z, c1.z);
        W1h[i][7] = __floats2half2_rn(a1.w, c1.w);
    }
    float W2col[8];
    #pragma unroll
    for (int jj = 0; jj < 8; ++jj) W2col[jj] = W2[jj * 8 + r];
    float b1u[8];
    #pragma unroll
    for (int j = 0; j < 8; ++j) b1u[j] = sgpr_f(b1[j]);
    const float b2r = b2[r];
    const float wpA = Wp[2 * r], wpB = Wp[2 * r + 1];
    const float bp0 = sgpr_f(bp[0]);

    const int wb = (blockIdx.x * 4 + wave) * (8 * EW_EPT);

    #pragma unroll
    for (int t = 0; t < EW_EPT; ++t) {
        const int e = wb + t * 8 + o;

        const int2 sd = *reinterpret_cast<const int2*>(&eidx[2 * e]);
        const float2 e2 = *reinterpret_cast<const float2*>(&edges[(size_t)e * 16 + 2 * r]);

        uint4 q4u = *reinterpret_cast<const uint4*>(&xq[(size_t)sd.x * 64 + 8 * r]);
        uint4 k4u = *reinterpret_cast<const uint4*>(&xk[(size_t)sd.y * 64 + 8 * r]);

        float p = fmaf(e2.x, wpA, e2.y * wpB);
        p = oct_sum(p) + bp0;

        const __half2 p2 = __float2half2_rn(p);
        const __half2* qh = reinterpret_cast<const __half2*>(&q4u);
        const __half2* kh = reinterpret_cast<const __half2*>(&k4u);

        float part[8];
        #pragma unroll
        for (int jj = 0; jj < 8; ++jj) part[jj] = 0.f;
        #pragma unroll
        for (int i = 0; i < 4; ++i) {
            const __half2 d = relu_h2(__hadd2(__hsub2(kh[i], qh[i]), p2));
            #pragma unroll
            for (int jj = 0; jj < 8; ++jj)
                part[jj] = fdot2f(d, W1h[i][jj], part[jj]);
        }
        #pragma unroll
        for (int jj = 0; jj < 8; ++jj) part[jj] = oct_sum(part[jj]);

        float h2 = b2r;
        #pragma unroll
        for (int jj = 0; jj < 8; ++jj) {
            const float h1 = fmaxf(part[jj] + b1u[jj], 0.f);
            h2 = fmaf(h1, W2col[jj], h2);
        }

        const float mx = oct_max(h2);
        const float ex = __expf(h2 - mx);
        const float sm = oct_sum(ex);
        const float w  = ex / sm;

        wout16[(size_t)e * 8 + r] = __half_as_ushort(__float2half_rn(w));
        if (r == 0) ep2e[e] = make_float2(p, __int_as_float(sd.y));
        if (r == 1) atomicAdd(&cnt[sd.x], 1);
    }
}

// ---------------------------------------------------------------------------
// Scatter: move precomputed {p,dst} + 16B weight record into CSR order.
// ---------------------------------------------------------------------------
__global__ __launch_bounds__(256) void scatter_kernel(
    const int* __restrict__ eidx, const float2* __restrict__ ep2e,
    const uint4* __restrict__ woute,
    int* __restrict__ cursor, float2* __restrict__ ep2, uint4* __restrict__ wcsr)
{
    const int e = blockIdx.x * 256 + threadIdx.x;
    const int src = eidx[2 * e];
    const float2 ep = ep2e[e];
    const uint4 w8 = woute[e];

    const int pos = atomicAdd(&cursor[src], 1);
    ep2[pos]  = ep;
    wcsr[pos] = w8;
}

// ---------------------------------------------------------------------------
// Node accumulation (r11-proven): 16 lanes per node (2 sub-octets, alternate
// edges). Lane r owns channels 8r..8r+7. Gather-FMA over CSR-ordered records.
// ---------------------------------------------------------------------------
__global__ __launch_bounds__(256) void node_accum(
    const int* __restrict__ off, const float2* __restrict__ ep2,
    const uint4* __restrict__ wcsr, const __half* __restrict__ xv,
    float* __restrict__ out)
{
    const int tid  = threadIdx.x;
    const int lane = tid & 63;
    const int grp  = lane >> 4;
    const int sub  = (lane >> 3) & 1;
    const int r    = lane & 7;
    const int wave = tid >> 6;

    const int node = blockIdx.x * 16 + wave * 4 + grp;

    const int beg = off[node];
    const int end = off[node + 1];

    float acc[8];
    #pragma unroll
    for (int i = 0; i < 8; ++i) acc[i] = 0.f;

    int j = beg + sub;
    float2 ep;
    uint4  w8;
    if (j < end) { ep = ep2[j]; w8 = wcsr[j]; }

    for (; j < end; j += 2) {
        const float p   = ep.x;
        const int   dst = __float_as_int(ep.y);

        union { uint4 u; __half2 h[4]; } v4, wz;
        v4.u = *reinterpret_cast<const uint4*>(&xv[(size_t)dst * 64 + 8 * r]);
        wz.u = w8;

        if (j + 2 < end) { ep = ep2[j + 2]; w8 = wcsr[j + 2]; }

        #pragma unroll
        for (int i = 0; i < 4; ++i) {
            const float2 fv = __half22float2(v4.h[i]);
            const float2 fw = __half22float2(wz.h[i]);
            acc[2 * i]     = fmaf(fv.x + p, fw.x, acc[2 * i]);
            acc[2 * i + 1] = fmaf(fv.y + p, fw.y, acc[2 * i + 1]);
        }
    }

    #pragma unroll
    for (int i = 0; i < 8; ++i)
        acc[i] += __shfl_xor(acc[i], 8);

    if (sub == 0) {
        float* orow = &out[(size_t)node * 64 + 8 * r];
        *reinterpret_cast<float4*>(orow)     = make_float4(acc[0], acc[1], acc[2], acc[3]);
        *reinterpret_cast<float4*>(orow + 4) = make_float4(acc[4], acc[5], acc[6], acc[7]);
    }
}

extern "C" void kernel_launch(void* const* d_in, const int* in_sizes, int n_in,
                              void* d_out, int out_size, void* d_ws, size_t ws_size,
                              hipStream_t stream) {
    const float* q     = (const float*)d_in[0];
    const float* k     = (const float*)d_in[1];
    const float* v     = (const float*)d_in[2];
    const float* edges = (const float*)d_in[3];
    const int*   eidx  = (const int*)d_in[4];
    const float* Wq    = (const float*)d_in[5];
    const float* bq    = (const float*)d_in[6];
    const float* Wk    = (const float*)d_in[7];
    const float* bk    = (const float*)d_in[8];
    const float* Wv    = (const float*)d_in[9];
    const float* bv    = (const float*)d_in[10];
    const float* Wp    = (const float*)d_in[11];
    const float* bp    = (const float*)d_in[12];
    const float* W1    = (const float*)d_in[13];
    const float* b1    = (const float*)d_in[14];
    const float* W2    = (const float*)d_in[15];
    const float* b2    = (const float*)d_in[16];
    float* out = (float*)d_out;

    // workspace layout
    char* ws = (char*)d_ws;
    __half* xq = (__half*)ws;          ws += (size_t)N_NODES * 64 * sizeof(__half);
    __half* xk = (__half*)ws;          ws += (size_t)N_NODES * 64 * sizeof(__half);
    __half* xv = (__half*)ws;          ws += (size_t)N_NODES * 64 * sizeof(__half);
    int* cnt  = (int*)ws;              ws += (size_t)(N_NODES + 64) * sizeof(int);
    int* off  = (int*)ws;              ws += (size_t)(N_NODES + 64) * sizeof(int);
    int* bsum = (int*)ws;              ws += (size_t)64 * sizeof(int);
    float2* ep2e = (float2*)ws;        ws += (size_t)E_EDGES * sizeof(float2);       // 6.4 MB
    ushort* wout = (ushort*)ws;        ws += (size_t)E_EDGES * 8 * sizeof(ushort);   // 12.8 MB
    float2* ep2  = (float2*)ws;        ws += (size_t)E_EDGES * sizeof(float2);       // 6.4 MB
    uint4*  wcsr = (uint4*)ws;         ws += (size_t)E_EDGES * sizeof(uint4);        // 12.8 MB

    // proj also zeroes cnt (replaces the memset dispatch)
    proj_kernel<<<dim3((N_NODES + 31) / 32), dim3(256), 0, stream>>>(
        q, k, v, Wq, bq, Wk, bk, Wv, bv, xq, xk, xv, cnt);

    // edge MLP + histogram (coalesced outputs, edge order)
    edge_weights<<<dim3(E_EDGES / (32 * EW_EPT)), dim3(256), 0, stream>>>(
        eidx, edges, Wp, bp, W1, b1, W2, b2, xq, xk, cnt, ep2e, wout);

    scan_sums<<<dim3(SCAN_NBLK), dim3(256), 0, stream>>>(cnt, bsum);
    scan_final<<<dim3(SCAN_NBLK), dim3(256), 0, stream>>>(cnt, bsum, off);

    scatter_kernel<<<dim3(E_EDGES / 256), dim3(256), 0, stream>>>(
        eidx, ep2e, (const uint4*)wout, cnt, ep2, wcsr);

    node_accum<<<dim3(N_NODES / 16), dim3(256), 0, stream>>>(
        off, ep2, wcsr, xv, out);
}

// Round 14
// 181.591 us; speedup vs baseline: 1.1631x; 1.1631x over previous
//
#include <hip/hip_runtime.h>
#include <hip/hip_fp16.h>

#define N_NODES 50000
#define E_EDGES 800000
#define SCAN_TILE 1024
#define SCAN_NBLK ((N_NODES + SCAN_TILE - 1) / SCAN_TILE)   // 49
#define EW_EPT 4    // edges per octet per wave-iteration

__device__ __forceinline__ float sgpr_f(float x) {
    return __uint_as_float(__builtin_amdgcn_readfirstlane(__float_as_uint(x)));
}

#if defined(__has_builtin)
#if __has_builtin(__builtin_amdgcn_fdot2)
#define HAS_FDOT2 1
#endif
#endif

typedef _Float16 v2h_t __attribute__((ext_vector_type(2)));

__device__ __forceinline__ float fdot2f(__half2 a, __half2 b, float c) {
#ifdef HAS_FDOT2
    return __builtin_amdgcn_fdot2(*reinterpret_cast<v2h_t*>(&a),
                                  *reinterpret_cast<v2h_t*>(&b), c, false);
#else
    const float2 fa = __half22float2(a);
    const float2 fb = __half22float2(b);
    return fmaf(fa.x, fb.x, fmaf(fa.y, fb.y, c));
#endif
}

// packed relu: v_pk_max_f16 with inline constant 0
__device__ __forceinline__ __half2 relu_h2(__half2 x) {
    union { __half2 h; unsigned u; } a, r;
    a.h = x;
    asm("v_pk_max_f16 %0, %1, 0" : "=v"(r.u) : "v"(a.u));
    return r.h;
}

// DPP cross-lane moves (VALU pipe, no LDS).
// 0xB1 = quad_perm lane^1, 0x4E = quad_perm lane^2,
// 0x141 = ROW_HALF_MIRROR (lane i <-> 7-i within aligned 8-lane groups).
template <int CTRL>
__device__ __forceinline__ float dpp_mov_f32(float x) {
    return __int_as_float(__builtin_amdgcn_update_dpp(
        0, __float_as_int(x), CTRL, 0xF, 0xF, true));
}
template <int CTRL>
__device__ __forceinline__ int dpp_mov_i32(int x) {
    return __builtin_amdgcn_update_dpp(0, x, CTRL, 0xF, 0xF, true);
}
// full 8-lane (octet) all-reduce (validated r11)
__device__ __forceinline__ float oct_sum(float x) {
    x += dpp_mov_f32<0xB1>(x);
    x += dpp_mov_f32<0x4E>(x);
    x += dpp_mov_f32<0x141>(x);
    return x;
}
__device__ __forceinline__ float oct_max(float x) {
    x = fmaxf(x, dpp_mov_f32<0xB1>(x));
    x = fmaxf(x, dpp_mov_f32<0x4E>(x));
    x = fmaxf(x, dpp_mov_f32<0x141>(x));
    return x;
}

// ---------------------------------------------------------------------------
// Projection kernel (r11-proven LDS version): xq,xk,xv = N x 64 fp16.
// ---------------------------------------------------------------------------
__global__ __launch_bounds__(256) void proj_kernel(
    const float* __restrict__ qin, const float* __restrict__ kin, const float* __restrict__ vin,
    const float* __restrict__ Wq, const float* __restrict__ bq,
    const float* __restrict__ Wk, const float* __restrict__ bk,
    const float* __restrict__ Wv, const float* __restrict__ bv,
    __half* __restrict__ xq, __half* __restrict__ xk, __half* __restrict__ xv)
{
    __shared__ float Ws[3 * 4096];
    const int tid = threadIdx.x;
    #pragma unroll
    for (int it = 0; it < 16; ++it) {
        const int idx = it * 256 + tid;
        Ws[idx]        = Wq[idx];
        Ws[4096 + idx] = Wk[idx];
        Ws[8192 + idx] = Wv[idx];
    }
    __syncthreads();

    const int cg = tid & 15;
    const int rg = tid >> 4;
    const int c0 = cg * 4;
    const int base = blockIdx.x * 64 + rg * 4;

    const float* ins[3]  = {qin, kin, vin};
    const float* bs[3]   = {bq, bk, bv};
    __half*      outs[3] = {xq, xk, xv};

    int rowi[4];
    #pragma unroll
    for (int rr = 0; rr < 4; ++rr)
        rowi[rr] = (base + rr < N_NODES) ? (base + rr) : (N_NODES - 1);

    #pragma unroll
    for (int m = 0; m < 3; ++m) {
        const float* in = ins[m];
        const float* Wm = &Ws[m * 4096];
        float4 acc[4];
        const float4 b4 = *reinterpret_cast<const float4*>(&bs[m][c0]);
        #pragma unroll
        for (int rr = 0; rr < 4; ++rr) acc[rr] = b4;

        for (int kk = 0; kk < 64; kk += 4) {
            float4 rv[4];
            #pragma unroll
            for (int rr = 0; rr < 4; ++rr)
                rv[rr] = *reinterpret_cast<const float4*>(&in[rowi[rr] * 64 + kk]);
            #pragma unroll
            for (int dk = 0; dk < 4; ++dk) {
                const float4 w4 = *reinterpret_cast<const float4*>(&Wm[(kk + dk) * 64 + c0]);
                #pragma unroll
                for (int rr = 0; rr < 4; ++rr) {
                    const float xs = reinterpret_cast<const float*>(&rv[rr])[dk];
                    acc[rr].x = fmaf(xs, w4.x, acc[rr].x);
                    acc[rr].y = fmaf(xs, w4.y, acc[rr].y);
                    acc[rr].z = fmaf(xs, w4.z, acc[rr].z);
                    acc[rr].w = fmaf(xs, w4.w, acc[rr].w);
                }
            }
        }
        #pragma unroll
        for (int rr = 0; rr < 4; ++rr) {
            if (base + rr < N_NODES) {
                union { __half2 h[2]; uint2 u; } pk;
                pk.h[0] = __floats2half2_rn(acc[rr].x, acc[rr].y);
                pk.h[1] = __floats2half2_rn(acc[rr].z, acc[rr].w);
                *reinterpret_cast<uint2*>(&outs[m][(size_t)(base + rr) * 64 + c0]) = pk.u;
            }
        }
    }
}

// ---------------------------------------------------------------------------
// Hierarchical scan, step A: per-1024-element block sums (49 blocks).
// ---------------------------------------------------------------------------
__global__ __launch_bounds__(256) void scan_sums(
    const int* __restrict__ cnt, int* __restrict__ bsum)
{
    const int tid  = threadIdx.x;
    const int base = blockIdx.x * SCAN_TILE + tid * 4;
    int s = 0;
    if (base + 3 < N_NODES) {
        const int4 t = *reinterpret_cast<const int4*>(&cnt[base]);
        s = t.x + t.y + t.z + t.w;
    } else {
        #pragma unroll
        for (int i = 0; i < 4; ++i)
            if (base + i < N_NODES) s += cnt[base + i];
    }
    #pragma unroll
    for (int d = 1; d < 64; d <<= 1) s += __shfl_xor(s, d);
    __shared__ int ws[4];
    if ((tid & 63) == 0) ws[tid >> 6] = s;
    __syncthreads();
    if (tid == 0) bsum[blockIdx.x] = ws[0] + ws[1] + ws[2] + ws[3];
}

// ---------------------------------------------------------------------------
// Hierarchical scan, step B: exclusive scan of the 49 block sums (one wave).
// ---------------------------------------------------------------------------
__global__ __launch_bounds__(64) void scan_bsum(int* __restrict__ bsum)
{
    const int lane = threadIdx.x;
    const int v = (lane < SCAN_NBLK) ? bsum[lane] : 0;
    int incl = v;
    #pragma unroll
    for (int d = 1; d < 64; d <<= 1) {
        const int t = __shfl_up(incl, d);
        if (lane >= d) incl += t;
    }
    if (lane < SCAN_NBLK) bsum[lane] = incl - v;
}

// ---------------------------------------------------------------------------
// Hierarchical scan, step C: local exclusive scan + block offset.
// Writes off[] and re-purposes cnt[] (in-place) as the scatter cursor.
// ---------------------------------------------------------------------------
__global__ __launch_bounds__(256) void scan_final(
    int* __restrict__ cnt, const int* __restrict__ bsum, int* __restrict__ off)
{
    const int tid  = threadIdx.x;
    const int base = blockIdx.x * SCAN_TILE + tid * 4;

    int v0 = 0, v1 = 0, v2 = 0, v3 = 0;
    if (base + 3 < N_NODES) {
        const int4 t = *reinterpret_cast<const int4*>(&cnt[base]);
        v0 = t.x; v1 = t.y; v2 = t.z; v3 = t.w;
    } else {
        if (base + 0 < N_NODES) v0 = cnt[base + 0];
        if (base + 1 < N_NODES) v1 = cnt[base + 1];
        if (base + 2 < N_NODES) v2 = cnt[base + 2];
        if (base + 3 < N_NODES) v3 = cnt[base + 3];
    }
    const int s = v0 + v1 + v2 + v3;

    int incl = s;
    #pragma unroll
    for (int d = 1; d < 64; d <<= 1) {
        const int t = __shfl_up(incl, d);
        if ((tid & 63) >= d) incl += t;
    }
    __shared__ int wsum[4];
    const int wave = tid >> 6;
    if ((tid & 63) == 63) wsum[wave] = incl;
    __syncthreads();
    int woff = 0;
    #pragma unroll
    for (int w = 0; w < 3; ++w)
        if (w < wave) woff += wsum[w];

    int run = bsum[blockIdx.x] + woff + (incl - s);
    if (base + 0 < N_NODES) { off[base + 0] = run; cnt[base + 0] = run; run += v0; }
    if (base + 1 < N_NODES) { off[base + 1] = run; cnt[base + 1] = run; run += v1; }
    if (base + 2 < N_NODES) { off[base + 2] = run; cnt[base + 2] = run; run += v2; }
    if (base + 3 < N_NODES) { off[base + 3] = run; cnt[base + 3] = run; run += v3; }

    if (blockIdx.x == 0 && tid == 0) off[N_NODES] = E_EDGES;
}

// ---------------------------------------------------------------------------
// Edge-weights kernel (r11 math) emitting ONE packed 16B record per edge:
//   word0 = src | (dst << 16)   (both < 65536)
//   word1 = w[0..3] as u8       (w quantized *255, deferred scale)
//   word2 = w[4..7] as u8
//   word3 = p as f32
// Weight bytes packed across the octet via integer DPP; lane 0 stores.
// ---------------------------------------------------------------------------
__global__ __launch_bounds__(256) void edge_weights(
    const int* __restrict__ eidx, const float* __restrict__ edges,
    const float* __restrict__ Wp, const float* __restrict__ bp,
    const float* __restrict__ W1, const float* __restrict__ b1,
    const float* __restrict__ W2, const float* __restrict__ b2,
    const __half* __restrict__ xq, const __half* __restrict__ xk,
    int* __restrict__ cnt, uint4* __restrict__ rece)
{
    const int tid  = threadIdx.x;
    const int lane = tid & 63;
    const int o    = lane >> 3;
    const int r    = lane & 7;
    const int wave = tid >> 6;

    __half2 W1h[4][8];
    #pragma unroll
    for (int i = 0; i < 4; ++i) {
        const float4 a0 = *reinterpret_cast<const float4*>(&W1[(8 * r + 2 * i) * 8]);
        const float4 a1 = *reinterpret_cast<const float4*>(&W1[(8 * r + 2 * i) * 8 + 4]);
        const float4 c0 = *reinterpret_cast<const float4*>(&W1[(8 * r + 2 * i + 1) * 8]);
        const float4 c1 = *reinterpret_cast<const float4*>(&W1[(8 * r + 2 * i + 1) * 8 + 4]);
        W1h[i][0] = __floats2half2_rn(a0.x, c0.x);
        W1h[i][1] = __floats2half2_rn(a0.y, c0.y);
        W1h[i][2] = __floats2half2_rn(a0.z, c0.z);
        W1h[i][3] = __floats2half2_rn(a0.w, c0.w);
        W1h[i][4] = __floats2half2_rn(a1.x, c1.x);
        W1h[i][5] = __floats2half2_rn(a1.y, c1.y);
        W1h[i][6] = __floats2half2_rn(a1.z, c1.z);
        W1h[i][7] = __floats2half2_rn(a1.w, c1.w);
    }
    float W2col[8];
    #pragma unroll
    for (int jj = 0; jj < 8; ++jj) W2col[jj] = W2[jj * 8 + r];
    float b1u[8];
    #pragma unroll
    for (int j = 0; j < 8; ++j) b1u[j] = sgpr_f(b1[j]);
    const float b2r = b2[r];
    const float wpA = Wp[2 * r], wpB = Wp[2 * r + 1];
    const float bp0 = sgpr_f(bp[0]);

    const int wb = (blockIdx.x * 4 + wave) * (8 * EW_EPT);

    #pragma unroll
    for (int t = 0; t < EW_EPT; ++t) {
        const int e = wb + t * 8 + o;

        const int2 sd = *reinterpret_cast<const int2*>(&eidx[2 * e]);
        const float2 e2 = *reinterpret_cast<const float2*>(&edges[(size_t)e * 16 + 2 * r]);

        uint4 q4u = *reinterpret_cast<const uint4*>(&xq[(size_t)sd.x * 64 + 8 * r]);
        uint4 k4u = *reinterpret_cast<const uint4*>(&xk[(size_t)sd.y * 64 + 8 * r]);

        float p = fmaf(e2.x, wpA, e2.y * wpB);
        p = oct_sum(p) + bp0;

        const __half2 p2 = __float2half2_rn(p);
        const __half2* qh = reinterpret_cast<const __half2*>(&q4u);
        const __half2* kh = reinterpret_cast<const __half2*>(&k4u);

        float part[8];
        #pragma unroll
        for (int jj = 0; jj < 8; ++jj) part[jj] = 0.f;
        #pragma unroll
        for (int i = 0; i < 4; ++i) {
            const __half2 d = relu_h2(__hadd2(__hsub2(kh[i], qh[i]), p2));
            #pragma unroll
            for (int jj = 0; jj < 8; ++jj)
                part[jj] = fdot2f(d, W1h[i][jj], part[jj]);
        }
        #pragma unroll
        for (int jj = 0; jj < 8; ++jj) part[jj] = oct_sum(part[jj]);

        float h2 = b2r;
        #pragma unroll
        for (int jj = 0; jj < 8; ++jj) {
            const float h1 = fmaxf(part[jj] + b1u[jj], 0.f);
            h2 = fmaf(h1, W2col[jj], h2);
        }

        const float mx = oct_max(h2);
        const float ex = __expf(h2 - mx);
        const float sm = oct_sum(ex);
        const float w  = ex / sm;

        // quantize to u8 (*255, deferred 1/255 in node_accum's epilogue)
        const unsigned wu = (unsigned)__float2uint_rn(w * 255.f);
        unsigned word = wu << (8 * (r & 3));
        word |= (unsigned)dpp_mov_i32<0xB1>((int)word);   // quad or-combine
        word |= (unsigned)dpp_mov_i32<0x4E>((int)word);
        const unsigned other = (unsigned)dpp_mov_i32<0x141>((int)word); // other quad's word

        if (r == 0) {
            uint4 rec;
            rec.x = (unsigned)sd.x | ((unsigned)sd.y << 16);
            rec.y = word;    // w[0..3]
            rec.z = other;   // w[4..7]
            rec.w = __float_as_uint(p);
            rece[e] = rec;   // coalesced: 8 octets -> 128B contiguous
        }
        if (r == 1) atomicAdd(&cnt[sd.x], 1);
    }
}

// ---------------------------------------------------------------------------
// Scatter: ONE random 16B store per edge (was 8B + 16B to two arrays).
// src comes from the record itself -> no eidx re-read.
// ---------------------------------------------------------------------------
__global__ __launch_bounds__(256) void scatter_kernel(
    const uint4* __restrict__ rece, int* __restrict__ cursor,
    uint4* __restrict__ reccsr)
{
    const int e = blockIdx.x * 256 + threadIdx.x;
    const uint4 rec = rece[e];
    const int src = (int)(rec.x & 0xFFFFu);
    const int pos = atomicAdd(&cursor[src], 1);
    reccsr[pos] = rec;
}

// ---------------------------------------------------------------------------
// Node accumulation: 16 lanes per node (2 sub-octets, alternate edges).
// Lane r owns channels 8r..8r+7; weight for channel 8r+i is u8 byte i of the
// record (deferred 1/255 applied at the end). Single linear record stream.
// ---------------------------------------------------------------------------
__global__ __launch_bounds__(256) void node_accum(
    const int* __restrict__ off, const uint4* __restrict__ reccsr,
    const __half* __restrict__ xv, float* __restrict__ out)
{
    const int tid  = threadIdx.x;
    const int lane = tid & 63;
    const int grp  = lane >> 4;
    const int sub  = (lane >> 3) & 1;
    const int r    = lane & 7;
    const int wave = tid >> 6;

    const int node = blockIdx.x * 16 + wave * 4 + grp;

    const int beg = off[node];
    const int end = off[node + 1];

    float acc[8];
    #pragma unroll
    for (int i = 0; i < 8; ++i) acc[i] = 0.f;

    int j = beg + sub;
    uint4 rec;
    if (j < end) rec = reccsr[j];

    for (; j < end; j += 2) {
        const uint4 cur = rec;
        const int   dst = (int)(cur.x >> 16);
        const float p   = __uint_as_float(cur.w);

        union { uint4 u; __half2 h[4]; } v4;
        v4.u = *reinterpret_cast<const uint4*>(&xv[(size_t)dst * 64 + 8 * r]);

        // prefetch next record (linear)
        if (j + 2 < end) rec = reccsr[j + 2];

        float wf[8];
        #pragma unroll
        for (int i = 0; i < 4; ++i) {
            wf[i]     = (float)((cur.y >> (8 * i)) & 255u);
            wf[4 + i] = (float)((cur.z >> (8 * i)) & 255u);
        }

        #pragma unroll
        for (int i = 0; i < 4; ++i) {
            const float2 fv = __half22float2(v4.h[i]);
            acc[2 * i]     = fmaf(fv.x + p, wf[2 * i],     acc[2 * i]);
            acc[2 * i + 1] = fmaf(fv.y + p, wf[2 * i + 1], acc[2 * i + 1]);
        }
    }

    // merge the two sub-octets
    #pragma unroll
    for (int i = 0; i < 8; ++i)
        acc[i] += __shfl_xor(acc[i], 8);

    if (sub == 0) {
        const float c = 1.f / 255.f;   // deferred weight scale
        float* orow = &out[(size_t)node * 64 + 8 * r];
        *reinterpret_cast<float4*>(orow) =
            make_float4(acc[0] * c, acc[1] * c, acc[2] * c, acc[3] * c);
        *reinterpret_cast<float4*>(orow + 4) =
            make_float4(acc[4] * c, acc[5] * c, acc[6] * c, acc[7] * c);
    }
}

extern "C" void kernel_launch(void* const* d_in, const int* in_sizes, int n_in,
                              void* d_out, int out_size, void* d_ws, size_t ws_size,
                              hipStream_t stream) {
    const float* q     = (const float*)d_in[0];
    const float* k     = (const float*)d_in[1];
    const float* v     = (const float*)d_in[2];
    const float* edges = (const float*)d_in[3];
    const int*   eidx  = (const int*)d_in[4];
    const float* Wq    = (const float*)d_in[5];
    const float* bq    = (const float*)d_in[6];
    const float* Wk    = (const float*)d_in[7];
    const float* bk    = (const float*)d_in[8];
    const float* Wv    = (const float*)d_in[9];
    const float* bv    = (const float*)d_in[10];
    const float* Wp    = (const float*)d_in[11];
    const float* bp    = (const float*)d_in[12];
    const float* W1    = (const float*)d_in[13];
    const float* b1    = (const float*)d_in[14];
    const float* W2    = (const float*)d_in[15];
    const float* b2    = (const float*)d_in[16];
    float* out = (float*)d_out;

    // workspace layout
    char* ws = (char*)d_ws;
    __half* xq = (__half*)ws;          ws += (size_t)N_NODES * 64 * sizeof(__half);
    __half* xk = (__half*)ws;          ws += (size_t)N_NODES * 64 * sizeof(__half);
    __half* xv = (__half*)ws;          ws += (size_t)N_NODES * 64 * sizeof(__half);
    int* cnt  = (int*)ws;              ws += (size_t)(N_NODES + 64) * sizeof(int);
    int* off  = (int*)ws;              ws += (size_t)(N_NODES + 64) * sizeof(int);
    int* bsum = (int*)ws;              ws += (size_t)64 * sizeof(int);
    uint4* rece   = (uint4*)ws;        ws += (size_t)E_EDGES * sizeof(uint4);   // 12.8 MB
    uint4* reccsr = (uint4*)ws;        ws += (size_t)E_EDGES * sizeof(uint4);   // 12.8 MB

    hipMemsetAsync(cnt, 0, (size_t)N_NODES * sizeof(int), stream);

    proj_kernel<<<dim3((N_NODES + 63) / 64), dim3(256), 0, stream>>>(
        q, k, v, Wq, bq, Wk, bk, Wv, bv, xq, xk, xv);

    edge_weights<<<dim3(E_EDGES / (32 * EW_EPT)), dim3(256), 0, stream>>>(
        eidx, edges, Wp, bp, W1, b1, W2, b2, xq, xk, cnt, rece);

    scan_sums<<<dim3(SCAN_NBLK), dim3(256), 0, stream>>>(cnt, bsum);
    scan_bsum<<<dim3(1), dim3(64), 0, stream>>>(bsum);
    scan_final<<<dim3(SCAN_NBLK), dim3(256), 0, stream>>>(cnt, bsum, off);

    scatter_kernel<<<dim3(E_EDGES / 256), dim3(256), 0, stream>>>(
        rece, cnt, reccsr);

    node_accum<<<dim3(N_NODES / 16), dim3(256), 0, stream>>>(
        off, reccsr, xv, out);
}

// Round 15
// 172.914 us; speedup vs baseline: 1.2215x; 1.0502x over previous
//
#include <hip/hip_runtime.h>
#include <hip/hip_fp16.h>

#define N_NODES 50000
#define E_EDGES 800000
#define SCAN_TILE 1024
#define SCAN_NBLK ((N_NODES + SCAN_TILE - 1) / SCAN_TILE)   // 49
#define EW_EPT 8    // edges per octet per wave-iteration (8 independent chains)

__device__ __forceinline__ float sgpr_f(float x) {
    return __uint_as_float(__builtin_amdgcn_readfirstlane(__float_as_uint(x)));
}

#if defined(__has_builtin)
#if __has_builtin(__builtin_amdgcn_fdot2)
#define HAS_FDOT2 1
#endif
#endif

typedef _Float16 v2h_t __attribute__((ext_vector_type(2)));

__device__ __forceinline__ float fdot2f(__half2 a, __half2 b, float c) {
#ifdef HAS_FDOT2
    return __builtin_amdgcn_fdot2(*reinterpret_cast<v2h_t*>(&a),
                                  *reinterpret_cast<v2h_t*>(&b), c, false);
#else
    const float2 fa = __half22float2(a);
    const float2 fb = __half22float2(b);
    return fmaf(fa.x, fb.x, fmaf(fa.y, fb.y, c));
#endif
}

// packed relu: v_pk_max_f16 with inline constant 0
__device__ __forceinline__ __half2 relu_h2(__half2 x) {
    union { __half2 h; unsigned u; } a, r;
    a.h = x;
    asm("v_pk_max_f16 %0, %1, 0" : "=v"(r.u) : "v"(a.u));
    return r.h;
}

// DPP cross-lane moves (VALU pipe, no LDS).
// 0xB1 = quad_perm lane^1, 0x4E = quad_perm lane^2,
// 0x141 = ROW_HALF_MIRROR (lane i <-> 7-i within aligned 8-lane groups).
template <int CTRL>
__device__ __forceinline__ float dpp_mov_f32(float x) {
    return __int_as_float(__builtin_amdgcn_update_dpp(
        0, __float_as_int(x), CTRL, 0xF, 0xF, true));
}
template <int CTRL>
__device__ __forceinline__ int dpp_mov_i32(int x) {
    return __builtin_amdgcn_update_dpp(0, x, CTRL, 0xF, 0xF, true);
}
// full 8-lane (octet) all-reduce (validated r11)
__device__ __forceinline__ float oct_sum(float x) {
    x += dpp_mov_f32<0xB1>(x);
    x += dpp_mov_f32<0x4E>(x);
    x += dpp_mov_f32<0x141>(x);
    return x;
}

// ---------------------------------------------------------------------------
// Projection kernel (r11-proven LDS version): xq,xk,xv = N x 64 fp16.
// ---------------------------------------------------------------------------
__global__ __launch_bounds__(256) void proj_kernel(
    const float* __restrict__ qin, const float* __restrict__ kin, const float* __restrict__ vin,
    const float* __restrict__ Wq, const float* __restrict__ bq,
    const float* __restrict__ Wk, const float* __restrict__ bk,
    const float* __restrict__ Wv, const float* __restrict__ bv,
    __half* __restrict__ xq, __half* __restrict__ xk, __half* __restrict__ xv)
{
    __shared__ float Ws[3 * 4096];
    const int tid = threadIdx.x;
    #pragma unroll
    for (int it = 0; it < 16; ++it) {
        const int idx = it * 256 + tid;
        Ws[idx]        = Wq[idx];
        Ws[4096 + idx] = Wk[idx];
        Ws[8192 + idx] = Wv[idx];
    }
    __syncthreads();

    const int cg = tid & 15;
    const int rg = tid >> 4;
    const int c0 = cg * 4;
    const int base = blockIdx.x * 64 + rg * 4;

    const float* ins[3]  = {qin, kin, vin};
    const float* bs[3]   = {bq, bk, bv};
    __half*      outs[3] = {xq, xk, xv};

    int rowi[4];
    #pragma unroll
    for (int rr = 0; rr < 4; ++rr)
        rowi[rr] = (base + rr < N_NODES) ? (base + rr) : (N_NODES - 1);

    #pragma unroll
    for (int m = 0; m < 3; ++m) {
        const float* in = ins[m];
        const float* Wm = &Ws[m * 4096];
        float4 acc[4];
        const float4 b4 = *reinterpret_cast<const float4*>(&bs[m][c0]);
        #pragma unroll
        for (int rr = 0; rr < 4; ++rr) acc[rr] = b4;

        for (int kk = 0; kk < 64; kk += 4) {
            float4 rv[4];
            #pragma unroll
            for (int rr = 0; rr < 4; ++rr)
                rv[rr] = *reinterpret_cast<const float4*>(&in[rowi[rr] * 64 + kk]);
            #pragma unroll
            for (int dk = 0; dk < 4; ++dk) {
                const float4 w4 = *reinterpret_cast<const float4*>(&Ws[m * 4096 + (kk + dk) * 64 + c0]);
                #pragma unroll
                for (int rr = 0; rr < 4; ++rr) {
                    const float xs = reinterpret_cast<const float*>(&rv[rr])[dk];
                    acc[rr].x = fmaf(xs, w4.x, acc[rr].x);
                    acc[rr].y = fmaf(xs, w4.y, acc[rr].y);
                    acc[rr].z = fmaf(xs, w4.z, acc[rr].z);
                    acc[rr].w = fmaf(xs, w4.w, acc[rr].w);
                }
            }
        }
        #pragma unroll
        for (int rr = 0; rr < 4; ++rr) {
            if (base + rr < N_NODES) {
                union { __half2 h[2]; uint2 u; } pk;
                pk.h[0] = __floats2half2_rn(acc[rr].x, acc[rr].y);
                pk.h[1] = __floats2half2_rn(acc[rr].z, acc[rr].w);
                *reinterpret_cast<uint2*>(&outs[m][(size_t)(base + rr) * 64 + c0]) = pk.u;
            }
        }
    }
}

// ---------------------------------------------------------------------------
// Hierarchical scan, step A: per-1024-element block sums (49 blocks).
// ---------------------------------------------------------------------------
__global__ __launch_bounds__(256) void scan_sums(
    const int* __restrict__ cnt, int* __restrict__ bsum)
{
    const int tid  = threadIdx.x;
    const int base = blockIdx.x * SCAN_TILE + tid * 4;
    int s = 0;
    if (base + 3 < N_NODES) {
        const int4 t = *reinterpret_cast<const int4*>(&cnt[base]);
        s = t.x + t.y + t.z + t.w;
    } else {
        #pragma unroll
        for (int i = 0; i < 4; ++i)
            if (base + i < N_NODES) s += cnt[base + i];
    }
    #pragma unroll
    for (int d = 1; d < 64; d <<= 1) s += __shfl_xor(s, d);
    __shared__ int ws[4];
    if ((tid & 63) == 0) ws[tid >> 6] = s;
    __syncthreads();
    if (tid == 0) bsum[blockIdx.x] = ws[0] + ws[1] + ws[2] + ws[3];
}

// ---------------------------------------------------------------------------
// Hierarchical scan, step B: exclusive scan of the 49 block sums (one wave).
// ---------------------------------------------------------------------------
__global__ __launch_bounds__(64) void scan_bsum(int* __restrict__ bsum)
{
    const int lane = threadIdx.x;
    const int v = (lane < SCAN_NBLK) ? bsum[lane] : 0;
    int incl = v;
    #pragma unroll
    for (int d = 1; d < 64; d <<= 1) {
        const int t = __shfl_up(incl, d);
        if (lane >= d) incl += t;
    }
    if (lane < SCAN_NBLK) bsum[lane] = incl - v;
}

// ---------------------------------------------------------------------------
// Hierarchical scan, step C: local exclusive scan + block offset.
// Writes off[] and re-purposes cnt[] (in-place) as the scatter cursor.
// ---------------------------------------------------------------------------
__global__ __launch_bounds__(256) void scan_final(
    int* __restrict__ cnt, const int* __restrict__ bsum, int* __restrict__ off)
{
    const int tid  = threadIdx.x;
    const int base = blockIdx.x * SCAN_TILE + tid * 4;

    int v0 = 0, v1 = 0, v2 = 0, v3 = 0;
    if (base + 3 < N_NODES) {
        const int4 t = *reinterpret_cast<const int4*>(&cnt[base]);
        v0 = t.x; v1 = t.y; v2 = t.z; v3 = t.w;
    } else {
        if (base + 0 < N_NODES) v0 = cnt[base + 0];
        if (base + 1 < N_NODES) v1 = cnt[base + 1];
        if (base + 2 < N_NODES) v2 = cnt[base + 2];
        if (base + 3 < N_NODES) v3 = cnt[base + 3];
    }
    const int s = v0 + v1 + v2 + v3;

    int incl = s;
    #pragma unroll
    for (int d = 1; d < 64; d <<= 1) {
        const int t = __shfl_up(incl, d);
        if ((tid & 63) >= d) incl += t;
    }
    __shared__ int wsum[4];
    const int wave = tid >> 6;
    if ((tid & 63) == 63) wsum[wave] = incl;
    __syncthreads();
    int woff = 0;
    #pragma unroll
    for (int w = 0; w < 3; ++w)
        if (w < wave) woff += wsum[w];

    int run = bsum[blockIdx.x] + woff + (incl - s);
    if (base + 0 < N_NODES) { off[base + 0] = run; cnt[base + 0] = run; run += v0; }
    if (base + 1 < N_NODES) { off[base + 1] = run; cnt[base + 1] = run; run += v1; }
    if (base + 2 < N_NODES) { off[base + 2] = run; cnt[base + 2] = run; run += v2; }
    if (base + 3 < N_NODES) { off[base + 3] = run; cnt[base + 3] = run; run += v3; }

    if (blockIdx.x == 0 && tid == 0) off[N_NODES] = E_EDGES;
}

// ---------------------------------------------------------------------------
// Edge-weights kernel (r14 record format, EW_EPT=8 for deeper MLP): emits one
// packed 16B record per edge:
//   word0 = src | (dst << 16); word1 = w[0..3] u8; word2 = w[4..7] u8;
//   word3 = p (f32).   Softmax without max-subtraction (logits bounded).
// ---------------------------------------------------------------------------
__global__ __launch_bounds__(256) void edge_weights(
    const int* __restrict__ eidx, const float* __restrict__ edges,
    const float* __restrict__ Wp, const float* __restrict__ bp,
    const float* __restrict__ W1, const float* __restrict__ b1,
    const float* __restrict__ W2, const float* __restrict__ b2,
    const __half* __restrict__ xq, const __half* __restrict__ xk,
    int* __restrict__ cnt, uint4* __restrict__ rece)
{
    const int tid  = threadIdx.x;
    const int lane = tid & 63;
    const int o    = lane >> 3;
    const int r    = lane & 7;
    const int wave = tid >> 6;

    __half2 W1h[4][8];
    #pragma unroll
    for (int i = 0; i < 4; ++i) {
        const float4 a0 = *reinterpret_cast<const float4*>(&W1[(8 * r + 2 * i) * 8]);
        const float4 a1 = *reinterpret_cast<const float4*>(&W1[(8 * r + 2 * i) * 8 + 4]);
        const float4 c0 = *reinterpret_cast<const float4*>(&W1[(8 * r + 2 * i + 1) * 8]);
        const float4 c1 = *reinterpret_cast<const float4*>(&W1[(8 * r + 2 * i + 1) * 8 + 4]);
        W1h[i][0] = __floats2half2_rn(a0.x, c0.x);
        W1h[i][1] = __floats2half2_rn(a0.y, c0.y);
        W1h[i][2] = __floats2half2_rn(a0.z, c0.z);
        W1h[i][3] = __floats2half2_rn(a0.w, c0.w);
        W1h[i][4] = __floats2half2_rn(a1.x, c1.x);
        W1h[i][5] = __floats2half2_rn(a1.y, c1.y);
        W1h[i][6] = __floats2half2_rn(a1.z, c1.z);
        W1h[i][7] = __floats2half2_rn(a1.w, c1.w);
    }
    float W2col[8];
    #pragma unroll
    for (int jj = 0; jj < 8; ++jj) W2col[jj] = W2[jj * 8 + r];
    float b1u[8];
    #pragma unroll
    for (int j = 0; j < 8; ++j) b1u[j] = sgpr_f(b1[j]);
    const float b2r = b2[r];
    const float wpA = Wp[2 * r], wpB = Wp[2 * r + 1];
    const float bp0 = sgpr_f(bp[0]);

    const int wb = (blockIdx.x * 4 + wave) * (8 * EW_EPT);

    #pragma unroll
    for (int t = 0; t < EW_EPT; ++t) {
        const int e = wb + t * 8 + o;

        const int2 sd = *reinterpret_cast<const int2*>(&eidx[2 * e]);
        const float2 e2 = *reinterpret_cast<const float2*>(&edges[(size_t)e * 16 + 2 * r]);

        uint4 q4u = *reinterpret_cast<const uint4*>(&xq[(size_t)sd.x * 64 + 8 * r]);
        uint4 k4u = *reinterpret_cast<const uint4*>(&xk[(size_t)sd.y * 64 + 8 * r]);

        float p = fmaf(e2.x, wpA, e2.y * wpB);
        p = oct_sum(p) + bp0;

        const __half2 p2 = __float2half2_rn(p);
        const __half2* qh = reinterpret_cast<const __half2*>(&q4u);
        const __half2* kh = reinterpret_cast<const __half2*>(&k4u);

        float part[8];
        #pragma unroll
        for (int jj = 0; jj < 8; ++jj) part[jj] = 0.f;
        #pragma unroll
        for (int i = 0; i < 4; ++i) {
            const __half2 d = relu_h2(__hadd2(__hsub2(kh[i], qh[i]), p2));
            #pragma unroll
            for (int jj = 0; jj < 8; ++jj)
                part[jj] = fdot2f(d, W1h[i][jj], part[jj]);
        }
        #pragma unroll
        for (int jj = 0; jj < 8; ++jj) part[jj] = oct_sum(part[jj]);

        float h2 = b2r;
        #pragma unroll
        for (int jj = 0; jj < 8; ++jj) {
            const float h1 = fmaxf(part[jj] + b1u[jj], 0.f);
            h2 = fmaf(h1, W2col[jj], h2);
        }

        // softmax without max-subtraction (|h2| << 88, f32-exp safe)
        const float ex = __expf(h2);
        const float sm = oct_sum(ex);
        const float w  = ex / sm;

        // quantize to u8 (*255, deferred 1/255 in node_accum's epilogue)
        const unsigned wu = (unsigned)__float2uint_rn(w * 255.f);
        unsigned word = wu << (8 * (r & 3));
        word |= (unsigned)dpp_mov_i32<0xB1>((int)word);   // quad or-combine
        word |= (unsigned)dpp_mov_i32<0x4E>((int)word);
        const unsigned other = (unsigned)dpp_mov_i32<0x141>((int)word); // other quad's word

        if (r == 0) {
            uint4 rec;
            rec.x = (unsigned)sd.x | ((unsigned)sd.y << 16);
            rec.y = word;    // w[0..3]
            rec.z = other;   // w[4..7]
            rec.w = __float_as_uint(p);
            rece[e] = rec;   // coalesced: 8 octets -> 128B contiguous
        }
        if (r == 1) atomicAdd(&cnt[sd.x], 1);
    }
}

// ---------------------------------------------------------------------------
// Scatter: ONE random 16B store per edge. src comes from the record.
// ---------------------------------------------------------------------------
__global__ __launch_bounds__(256) void scatter_kernel(
    const uint4* __restrict__ rece, int* __restrict__ cursor,
    uint4* __restrict__ reccsr)
{
    const int e = blockIdx.x * 256 + threadIdx.x;
    const uint4 rec = rece[e];
    const int src = (int)(rec.x & 0xFFFFu);
    const int pos = atomicAdd(&cursor[src], 1);
    reccsr[pos] = rec;
}

// ---------------------------------------------------------------------------
// Node accumulation (r14-proven): 16 lanes per node (2 sub-octets, alternate
// edges). Lane r owns channels 8r..8r+7; weights u8 with deferred 1/255.
// ---------------------------------------------------------------------------
__global__ __launch_bounds__(256) void node_accum(
    const int* __restrict__ off, const uint4* __restrict__ reccsr,
    const __half* __restrict__ xv, float* __restrict__ out)
{
    const int tid  = threadIdx.x;
    const int lane = tid & 63;
    const int grp  = lane >> 4;
    const int sub  = (lane >> 3) & 1;
    const int r    = lane & 7;
    const int wave = tid >> 6;

    const int node = blockIdx.x * 16 + wave * 4 + grp;

    const int beg = off[node];
    const int end = off[node + 1];

    float acc[8];
    #pragma unroll
    for (int i = 0; i < 8; ++i) acc[i] = 0.f;

    int j = beg + sub;
    uint4 rec;
    if (j < end) rec = reccsr[j];

    for (; j < end; j += 2) {
        const uint4 cur = rec;
        const int   dst = (int)(cur.x >> 16);
        const float p   = __uint_as_float(cur.w);

        union { uint4 u; __half2 h[4]; } v4;
        v4.u = *reinterpret_cast<const uint4*>(&xv[(size_t)dst * 64 + 8 * r]);

        if (j + 2 < end) rec = reccsr[j + 2];

        float wf[8];
        #pragma unroll
        for (int i = 0; i < 4; ++i) {
            wf[i]     = (float)((cur.y >> (8 * i)) & 255u);
            wf[4 + i] = (float)((cur.z >> (8 * i)) & 255u);
        }

        #pragma unroll
        for (int i = 0; i < 4; ++i) {
            const float2 fv = __half22float2(v4.h[i]);
            acc[2 * i]     = fmaf(fv.x + p, wf[2 * i],     acc[2 * i]);
            acc[2 * i + 1] = fmaf(fv.y + p, wf[2 * i + 1], acc[2 * i + 1]);
        }
    }

    #pragma unroll
    for (int i = 0; i < 8; ++i)
        acc[i] += __shfl_xor(acc[i], 8);

    if (sub == 0) {
        const float c = 1.f / 255.f;
        float* orow = &out[(size_t)node * 64 + 8 * r];
        *reinterpret_cast<float4*>(orow) =
            make_float4(acc[0] * c, acc[1] * c, acc[2] * c, acc[3] * c);
        *reinterpret_cast<float4*>(orow + 4) =
            make_float4(acc[4] * c, acc[5] * c, acc[6] * c, acc[7] * c);
    }
}

extern "C" void kernel_launch(void* const* d_in, const int* in_sizes, int n_in,
                              void* d_out, int out_size, void* d_ws, size_t ws_size,
                              hipStream_t stream) {
    const float* q     = (const float*)d_in[0];
    const float* k     = (const float*)d_in[1];
    const float* v     = (const float*)d_in[2];
    const float* edges = (const float*)d_in[3];
    const int*   eidx  = (const int*)d_in[4];
    const float* Wq    = (const float*)d_in[5];
    const float* bq    = (const float*)d_in[6];
    const float* Wk    = (const float*)d_in[7];
    const float* bk    = (const float*)d_in[8];
    const float* Wv    = (const float*)d_in[9];
    const float* bv    = (const float*)d_in[10];
    const float* Wp    = (const float*)d_in[11];
    const float* bp    = (const float*)d_in[12];
    const float* W1    = (const float*)d_in[13];
    const float* b1    = (const float*)d_in[14];
    const float* W2    = (const float*)d_in[15];
    const float* b2    = (const float*)d_in[16];
    float* out = (float*)d_out;

    // workspace layout
    char* ws = (char*)d_ws;
    __half* xq = (__half*)ws;          ws += (size_t)N_NODES * 64 * sizeof(__half);
    __half* xk = (__half*)ws;          ws += (size_t)N_NODES * 64 * sizeof(__half);
    __half* xv = (__half*)ws;          ws += (size_t)N_NODES * 64 * sizeof(__half);
    int* cnt  = (int*)ws;              ws += (size_t)(N_NODES + 64) * sizeof(int);
    int* off  = (int*)ws;              ws += (size_t)(N_NODES + 64) * sizeof(int);
    int* bsum = (int*)ws;              ws += (size_t)64 * sizeof(int);
    uint4* rece   = (uint4*)ws;        ws += (size_t)E_EDGES * sizeof(uint4);   // 12.8 MB
    uint4* reccsr = (uint4*)ws;        ws += (size_t)E_EDGES * sizeof(uint4);   // 12.8 MB

    hipMemsetAsync(cnt, 0, (size_t)N_NODES * sizeof(int), stream);

    proj_kernel<<<dim3((N_NODES + 63) / 64), dim3(256), 0, stream>>>(
        q, k, v, Wq, bq, Wk, bk, Wv, bv, xq, xk, xv);

    edge_weights<<<dim3(E_EDGES / (32 * EW_EPT)), dim3(256), 0, stream>>>(
        eidx, edges, Wp, bp, W1, b1, W2, b2, xq, xk, cnt, rece);

    scan_sums<<<dim3(SCAN_NBLK), dim3(256), 0, stream>>>(cnt, bsum);
    scan_bsum<<<dim3(1), dim3(64), 0, stream>>>(bsum);
    scan_final<<<dim3(SCAN_NBLK), dim3(256), 0, stream>>>(cnt, bsum, off);

    scatter_kernel<<<dim3(E_EDGES / 256), dim3(256), 0, stream>>>(
        rece, cnt, reccsr);

    node_accum<<<dim3(N_NODES / 16), dim3(256), 0, stream>>>(
        off, reccsr, xv, out);
}

// Round 16
// 171.835 us; speedup vs baseline: 1.2292x; 1.0063x over previous
//
#include <hip/hip_runtime.h>
#include <hip/hip_fp16.h>

#define N_NODES 50000
#define E_EDGES 800000
#define SCAN_TILE 1024
#define SCAN_NBLK ((N_NODES + SCAN_TILE - 1) / SCAN_TILE)   // 49
#define EW_EPT 8    // edges per octet per wave-iteration (8 independent chains)

__device__ __forceinline__ float sgpr_f(float x) {
    return __uint_as_float(__builtin_amdgcn_readfirstlane(__float_as_uint(x)));
}

#if defined(__has_builtin)
#if __has_builtin(__builtin_amdgcn_fdot2)
#define HAS_FDOT2 1
#endif
#endif

typedef _Float16 v2h_t __attribute__((ext_vector_type(2)));

__device__ __forceinline__ float fdot2f(__half2 a, __half2 b, float c) {
#ifdef HAS_FDOT2
    return __builtin_amdgcn_fdot2(*reinterpret_cast<v2h_t*>(&a),
                                  *reinterpret_cast<v2h_t*>(&b), c, false);
#else
    const float2 fa = __half22float2(a);
    const float2 fb = __half22float2(b);
    return fmaf(fa.x, fb.x, fmaf(fa.y, fb.y, c));
#endif
}

// packed relu: v_pk_max_f16 with inline constant 0
__device__ __forceinline__ __half2 relu_h2(__half2 x) {
    union { __half2 h; unsigned u; } a, r;
    a.h = x;
    asm("v_pk_max_f16 %0, %1, 0" : "=v"(r.u) : "v"(a.u));
    return r.h;
}

// DPP cross-lane moves (VALU pipe, no LDS).
// 0xB1 = quad_perm lane^1, 0x4E = quad_perm lane^2,
// 0x141 = ROW_HALF_MIRROR (lane i <-> 7-i within aligned 8-lane groups).
template <int CTRL>
__device__ __forceinline__ float dpp_mov_f32(float x) {
    return __int_as_float(__builtin_amdgcn_update_dpp(
        0, __float_as_int(x), CTRL, 0xF, 0xF, true));
}
template <int CTRL>
__device__ __forceinline__ int dpp_mov_i32(int x) {
    return __builtin_amdgcn_update_dpp(0, x, CTRL, 0xF, 0xF, true);
}
// full 8-lane (octet) all-reduce (validated r11)
__device__ __forceinline__ float oct_sum(float x) {
    x += dpp_mov_f32<0xB1>(x);
    x += dpp_mov_f32<0x4E>(x);
    x += dpp_mov_f32<0x141>(x);
    return x;
}

// ---------------------------------------------------------------------------
// Projection kernel, fp16-dot2 version: W staged in LDS as half2 k-pairs
// (24 KB), inputs converted to half2, fdot2 with f32 accumulate -> VALU work
// halves vs f32 FMA. Same 64 rows x 64 cols / block decomposition.
// ---------------------------------------------------------------------------
__global__ __launch_bounds__(256) void proj_kernel(
    const float* __restrict__ qin, const float* __restrict__ kin, const float* __restrict__ vin,
    const float* __restrict__ Wq, const float* __restrict__ bq,
    const float* __restrict__ Wk, const float* __restrict__ bk,
    const float* __restrict__ Wv, const float* __restrict__ bv,
    __half* __restrict__ xq, __half* __restrict__ xk, __half* __restrict__ xv)
{
    // Wh[m][kp][c]: half2 {W[2kp][c], W[2kp+1][c]}, kp=0..31, c=0..63
    __shared__ unsigned Wh[3 * 2048];
    const int tid = threadIdx.x;
    #pragma unroll
    for (int it = 0; it < 8; ++it) {
        const int idx = it * 256 + tid;          // 0..2047
        const int kp = idx >> 6, c = idx & 63;
        {
            const __half2 h = __floats2half2_rn(Wq[(2 * kp) * 64 + c], Wq[(2 * kp + 1) * 64 + c]);
            Wh[idx] = *reinterpret_cast<const unsigned*>(&h);
        }
        {
            const __half2 h = __floats2half2_rn(Wk[(2 * kp) * 64 + c], Wk[(2 * kp + 1) * 64 + c]);
            Wh[2048 + idx] = *reinterpret_cast<const unsigned*>(&h);
        }
        {
            const __half2 h = __floats2half2_rn(Wv[(2 * kp) * 64 + c], Wv[(2 * kp + 1) * 64 + c]);
            Wh[4096 + idx] = *reinterpret_cast<const unsigned*>(&h);
        }
    }
    __syncthreads();

    const int cg = tid & 15;
    const int rg = tid >> 4;
    const int c0 = cg * 4;
    const int base = blockIdx.x * 64 + rg * 4;

    const float* ins[3]  = {qin, kin, vin};
    const float* bs[3]   = {bq, bk, bv};
    __half*      outs[3] = {xq, xk, xv};

    int rowi[4];
    #pragma unroll
    for (int rr = 0; rr < 4; ++rr)
        rowi[rr] = (base + rr < N_NODES) ? (base + rr) : (N_NODES - 1);

    #pragma unroll
    for (int m = 0; m < 3; ++m) {
        const float* in = ins[m];
        float4 acc[4];
        const float4 b4 = *reinterpret_cast<const float4*>(&bs[m][c0]);
        #pragma unroll
        for (int rr = 0; rr < 4; ++rr) acc[rr] = b4;

        for (int kk = 0; kk < 64; kk += 4) {
            __half2 xp[4][2];
            #pragma unroll
            for (int rr = 0; rr < 4; ++rr) {
                const float4 rv = *reinterpret_cast<const float4*>(&in[rowi[rr] * 64 + kk]);
                xp[rr][0] = __floats2half2_rn(rv.x, rv.y);
                xp[rr][1] = __floats2half2_rn(rv.z, rv.w);
            }
            #pragma unroll
            for (int h = 0; h < 2; ++h) {
                const int kp = (kk >> 1) + h;
                const uint4 wq = *reinterpret_cast<const uint4*>(&Wh[m * 2048 + kp * 64 + c0]);
                const __half2 w0 = *reinterpret_cast<const __half2*>(&wq.x);
                const __half2 w1 = *reinterpret_cast<const __half2*>(&wq.y);
                const __half2 w2 = *reinterpret_cast<const __half2*>(&wq.z);
                const __half2 w3 = *reinterpret_cast<const __half2*>(&wq.w);
                #pragma unroll
                for (int rr = 0; rr < 4; ++rr) {
                    acc[rr].x = fdot2f(xp[rr][h], w0, acc[rr].x);
                    acc[rr].y = fdot2f(xp[rr][h], w1, acc[rr].y);
                    acc[rr].z = fdot2f(xp[rr][h], w2, acc[rr].z);
                    acc[rr].w = fdot2f(xp[rr][h], w3, acc[rr].w);
                }
            }
        }
        #pragma unroll
        for (int rr = 0; rr < 4; ++rr) {
            if (base + rr < N_NODES) {
                union { __half2 h[2]; uint2 u; } pk;
                pk.h[0] = __floats2half2_rn(acc[rr].x, acc[rr].y);
                pk.h[1] = __floats2half2_rn(acc[rr].z, acc[rr].w);
                *reinterpret_cast<uint2*>(&outs[m][(size_t)(base + rr) * 64 + c0]) = pk.u;
            }
        }
    }
}

// ---------------------------------------------------------------------------
// CSR build step 1: per-src degree histogram (back, since edge_weights now
// needs the finished cursor before it runs).
// ---------------------------------------------------------------------------
__global__ __launch_bounds__(256) void hist_kernel(
    const int* __restrict__ eidx, int* __restrict__ cnt)
{
    const int e = blockIdx.x * 256 + threadIdx.x;
    atomicAdd(&cnt[eidx[2 * e]], 1);
}

// ---------------------------------------------------------------------------
// Hierarchical scan, step A: per-1024-element block sums (49 blocks).
// ---------------------------------------------------------------------------
__global__ __launch_bounds__(256) void scan_sums(
    const int* __restrict__ cnt, int* __restrict__ bsum)
{
    const int tid  = threadIdx.x;
    const int base = blockIdx.x * SCAN_TILE + tid * 4;
    int s = 0;
    if (base + 3 < N_NODES) {
        const int4 t = *reinterpret_cast<const int4*>(&cnt[base]);
        s = t.x + t.y + t.z + t.w;
    } else {
        #pragma unroll
        for (int i = 0; i < 4; ++i)
            if (base + i < N_NODES) s += cnt[base + i];
    }
    #pragma unroll
    for (int d = 1; d < 64; d <<= 1) s += __shfl_xor(s, d);
    __shared__ int ws[4];
    if ((tid & 63) == 0) ws[tid >> 6] = s;
    __syncthreads();
    if (tid == 0) bsum[blockIdx.x] = ws[0] + ws[1] + ws[2] + ws[3];
}

// ---------------------------------------------------------------------------
// Hierarchical scan, step B: exclusive scan of the 49 block sums (one wave).
// ---------------------------------------------------------------------------
__global__ __launch_bounds__(64) void scan_bsum(int* __restrict__ bsum)
{
    const int lane = threadIdx.x;
    const int v = (lane < SCAN_NBLK) ? bsum[lane] : 0;
    int incl = v;
    #pragma unroll
    for (int d = 1; d < 64; d <<= 1) {
        const int t = __shfl_up(incl, d);
        if (lane >= d) incl += t;
    }
    if (lane < SCAN_NBLK) bsum[lane] = incl - v;
}

// ---------------------------------------------------------------------------
// Hierarchical scan, step C: local exclusive scan + block offset.
// Writes off[] and re-purposes cnt[] (in-place) as the CSR cursor.
// ---------------------------------------------------------------------------
__global__ __launch_bounds__(256) void scan_final(
    int* __restrict__ cnt, const int* __restrict__ bsum, int* __restrict__ off)
{
    const int tid  = threadIdx.x;
    const int base = blockIdx.x * SCAN_TILE + tid * 4;

    int v0 = 0, v1 = 0, v2 = 0, v3 = 0;
    if (base + 3 < N_NODES) {
        const int4 t = *reinterpret_cast<const int4*>(&cnt[base]);
        v0 = t.x; v1 = t.y; v2 = t.z; v3 = t.w;
    } else {
        if (base + 0 < N_NODES) v0 = cnt[base + 0];
        if (base + 1 < N_NODES) v1 = cnt[base + 1];
        if (base + 2 < N_NODES) v2 = cnt[base + 2];
        if (base + 3 < N_NODES) v3 = cnt[base + 3];
    }
    const int s = v0 + v1 + v2 + v3;

    int incl = s;
    #pragma unroll
    for (int d = 1; d < 64; d <<= 1) {
        const int t = __shfl_up(incl, d);
        if ((tid & 63) >= d) incl += t;
    }
    __shared__ int wsum[4];
    const int wave = tid >> 6;
    if ((tid & 63) == 63) wsum[wave] = incl;
    __syncthreads();
    int woff = 0;
    #pragma unroll
    for (int w = 0; w < 3; ++w)
        if (w < wave) woff += wsum[w];

    int run = bsum[blockIdx.x] + woff + (incl - s);
    if (base + 0 < N_NODES) { off[base + 0] = run; cnt[base + 0] = run; run += v0; }
    if (base + 1 < N_NODES) { off[base + 1] = run; cnt[base + 1] = run; run += v1; }
    if (base + 2 < N_NODES) { off[base + 2] = run; cnt[base + 2] = run; run += v2; }
    if (base + 3 < N_NODES) { off[base + 3] = run; cnt[base + 3] = run; run += v3; }

    if (blockIdx.x == 0 && tid == 0) off[N_NODES] = E_EDGES;
}

// ---------------------------------------------------------------------------
// Edge-weights kernel with DIRECT single-record CSR write: lane 0 claims the
// slot (cursor atomic) and stores the packed 16B record straight to its CSR
// position. No intermediate edge-order array, no separate scatter pass.
// Record: word0 = src | (dst<<16); word1 = w[0..3] u8; word2 = w[4..7] u8;
//         word3 = p (f32). Softmax without max-subtraction.
// ---------------------------------------------------------------------------
__global__ __launch_bounds__(256) void edge_weights(
    const int* __restrict__ eidx, const float* __restrict__ edges,
    const float* __restrict__ Wp, const float* __restrict__ bp,
    const float* __restrict__ W1, const float* __restrict__ b1,
    const float* __restrict__ W2, const float* __restrict__ b2,
    const __half* __restrict__ xq, const __half* __restrict__ xk,
    int* __restrict__ cursor, uint4* __restrict__ reccsr)
{
    const int tid  = threadIdx.x;
    const int lane = tid & 63;
    const int o    = lane >> 3;
    const int r    = lane & 7;
    const int wave = tid >> 6;

    __half2 W1h[4][8];
    #pragma unroll
    for (int i = 0; i < 4; ++i) {
        const float4 a0 = *reinterpret_cast<const float4*>(&W1[(8 * r + 2 * i) * 8]);
        const float4 a1 = *reinterpret_cast<const float4*>(&W1[(8 * r + 2 * i) * 8 + 4]);
        const float4 c0 = *reinterpret_cast<const float4*>(&W1[(8 * r + 2 * i + 1) * 8]);
        const float4 c1 = *reinterpret_cast<const float4*>(&W1[(8 * r + 2 * i + 1) * 8 + 4]);
        W1h[i][0] = __floats2half2_rn(a0.x, c0.x);
        W1h[i][1] = __floats2half2_rn(a0.y, c0.y);
        W1h[i][2] = __floats2half2_rn(a0.z, c0.z);
        W1h[i][3] = __floats2half2_rn(a0.w, c0.w);
        W1h[i][4] = __floats2half2_rn(a1.x, c1.x);
        W1h[i][5] = __floats2half2_rn(a1.y, c1.y);
        W1h[i][6] = __floats2half2_rn(a1.z, c1.z);
        W1h[i][7] = __floats2half2_rn(a1.w, c1.w);
    }
    float W2col[8];
    #pragma unroll
    for (int jj = 0; jj < 8; ++jj) W2col[jj] = W2[jj * 8 + r];
    float b1u[8];
    #pragma unroll
    for (int j = 0; j < 8; ++j) b1u[j] = sgpr_f(b1[j]);
    const float b2r = b2[r];
    const float wpA = Wp[2 * r], wpB = Wp[2 * r + 1];
    const float bp0 = sgpr_f(bp[0]);

    const int wb = (blockIdx.x * 4 + wave) * (8 * EW_EPT);

    #pragma unroll
    for (int t = 0; t < EW_EPT; ++t) {
        const int e = wb + t * 8 + o;

        const int2 sd = *reinterpret_cast<const int2*>(&eidx[2 * e]);
        const float2 e2 = *reinterpret_cast<const float2*>(&edges[(size_t)e * 16 + 2 * r]);

        uint4 q4u = *reinterpret_cast<const uint4*>(&xq[(size_t)sd.x * 64 + 8 * r]);
        uint4 k4u = *reinterpret_cast<const uint4*>(&xk[(size_t)sd.y * 64 + 8 * r]);

        float p = fmaf(e2.x, wpA, e2.y * wpB);
        p = oct_sum(p) + bp0;

        const __half2 p2 = __float2half2_rn(p);
        const __half2* qh = reinterpret_cast<const __half2*>(&q4u);
        const __half2* kh = reinterpret_cast<const __half2*>(&k4u);

        float part[8];
        #pragma unroll
        for (int jj = 0; jj < 8; ++jj) part[jj] = 0.f;
        #pragma unroll
        for (int i = 0; i < 4; ++i) {
            const __half2 d = relu_h2(__hadd2(__hsub2(kh[i], qh[i]), p2));
            #pragma unroll
            for (int jj = 0; jj < 8; ++jj)
                part[jj] = fdot2f(d, W1h[i][jj], part[jj]);
        }
        #pragma unroll
        for (int jj = 0; jj < 8; ++jj) part[jj] = oct_sum(part[jj]);

        float h2 = b2r;
        #pragma unroll
        for (int jj = 0; jj < 8; ++jj) {
            const float h1 = fmaxf(part[jj] + b1u[jj], 0.f);
            h2 = fmaf(h1, W2col[jj], h2);
        }

        // softmax without max-subtraction (|h2| << 88, f32-exp safe)
        const float ex = __expf(h2);
        const float sm = oct_sum(ex);
        const float w  = ex / sm;

        // quantize to u8 (*255, deferred 1/255 in node_accum's epilogue)
        const unsigned wu = (unsigned)__float2uint_rn(w * 255.f);
        unsigned word = wu << (8 * (r & 3));
        word |= (unsigned)dpp_mov_i32<0xB1>((int)word);   // quad or-combine
        word |= (unsigned)dpp_mov_i32<0x4E>((int)word);
        const unsigned other = (unsigned)dpp_mov_i32<0x141>((int)word); // other quad's word

        if (r == 0) {
            uint4 rec;
            rec.x = (unsigned)sd.x | ((unsigned)sd.y << 16);
            rec.y = word;    // w[0..3]
            rec.z = other;   // w[4..7]
            rec.w = __float_as_uint(p);
            const int pos = atomicAdd(&cursor[sd.x], 1);
            reccsr[pos] = rec;   // one random 16B store per edge
        }
    }
}

// ---------------------------------------------------------------------------
// Node accumulation (r14-proven): 16 lanes per node (2 sub-octets, alternate
// edges). Lane r owns channels 8r..8r+7; weights u8 with deferred 1/255.
// ---------------------------------------------------------------------------
__global__ __launch_bounds__(256) void node_accum(
    const int* __restrict__ off, const uint4* __restrict__ reccsr,
    const __half* __restrict__ xv, float* __restrict__ out)
{
    const int tid  = threadIdx.x;
    const int lane = tid & 63;
    const int grp  = lane >> 4;
    const int sub  = (lane >> 3) & 1;
    const int r    = lane & 7;
    const int wave = tid >> 6;

    const int node = blockIdx.x * 16 + wave * 4 + grp;

    const int beg = off[node];
    const int end = off[node + 1];

    float acc[8];
    #pragma unroll
    for (int i = 0; i < 8; ++i) acc[i] = 0.f;

    int j = beg + sub;
    uint4 rec;
    if (j < end) rec = reccsr[j];

    for (; j < end; j += 2) {
        const uint4 cur = rec;
        const int   dst = (int)(cur.x >> 16);
        const float p   = __uint_as_float(cur.w);

        union { uint4 u; __half2 h[4]; } v4;
        v4.u = *reinterpret_cast<const uint4*>(&xv[(size_t)dst * 64 + 8 * r]);

        if (j + 2 < end) rec = reccsr[j + 2];

        float wf[8];
        #pragma unroll
        for (int i = 0; i < 4; ++i) {
            wf[i]     = (float)((cur.y >> (8 * i)) & 255u);
            wf[4 + i] = (float)((cur.z >> (8 * i)) & 255u);
        }

        #pragma unroll
        for (int i = 0; i < 4; ++i) {
            const float2 fv = __half22float2(v4.h[i]);
            acc[2 * i]     = fmaf(fv.x + p, wf[2 * i],     acc[2 * i]);
            acc[2 * i + 1] = fmaf(fv.y + p, wf[2 * i + 1], acc[2 * i + 1]);
        }
    }

    #pragma unroll
    for (int i = 0; i < 8; ++i)
        acc[i] += __shfl_xor(acc[i], 8);

    if (sub == 0) {
        const float c = 1.f / 255.f;
        float* orow = &out[(size_t)node * 64 + 8 * r];
        *reinterpret_cast<float4*>(orow) =
            make_float4(acc[0] * c, acc[1] * c, acc[2] * c, acc[3] * c);
        *reinterpret_cast<float4*>(orow + 4) =
            make_float4(acc[4] * c, acc[5] * c, acc[6] * c, acc[7] * c);
    }
}

extern "C" void kernel_launch(void* const* d_in, const int* in_sizes, int n_in,
                              void* d_out, int out_size, void* d_ws, size_t ws_size,
                              hipStream_t stream) {
    const float* q     = (const float*)d_in[0];
    const float* k     = (const float*)d_in[1];
    const float* v     = (const float*)d_in[2];
    const float* edges = (const float*)d_in[3];
    const int*   eidx  = (const int*)d_in[4];
    const float* Wq    = (const float*)d_in[5];
    const float* bq    = (const float*)d_in[6];
    const float* Wk    = (const float*)d_in[7];
    const float* bk    = (const float*)d_in[8];
    const float* Wv    = (const float*)d_in[9];
    const float* bv    = (const float*)d_in[10];
    const float* Wp    = (const float*)d_in[11];
    const float* bp    = (const float*)d_in[12];
    const float* W1    = (const float*)d_in[13];
    const float* b1    = (const float*)d_in[14];
    const float* W2    = (const float*)d_in[15];
    const float* b2    = (const float*)d_in[16];
    float* out = (float*)d_out;

    // workspace layout
    char* ws = (char*)d_ws;
    __half* xq = (__half*)ws;          ws += (size_t)N_NODES * 64 * sizeof(__half);
    __half* xk = (__half*)ws;          ws += (size_t)N_NODES * 64 * sizeof(__half);
    __half* xv = (__half*)ws;          ws += (size_t)N_NODES * 64 * sizeof(__half);
    int* cnt  = (int*)ws;              ws += (size_t)(N_NODES + 64) * sizeof(int);
    int* off  = (int*)ws;              ws += (size_t)(N_NODES + 64) * sizeof(int);
    int* bsum = (int*)ws;              ws += (size_t)64 * sizeof(int);
    uint4* reccsr = (uint4*)ws;        ws += (size_t)E_EDGES * sizeof(uint4);   // 12.8 MB

    hipMemsetAsync(cnt, 0, (size_t)N_NODES * sizeof(int), stream);

    // CSR structure first (depends only on eidx)...
    hist_kernel<<<dim3(E_EDGES / 256), dim3(256), 0, stream>>>(eidx, cnt);
    scan_sums<<<dim3(SCAN_NBLK), dim3(256), 0, stream>>>(cnt, bsum);
    scan_bsum<<<dim3(1), dim3(64), 0, stream>>>(bsum);
    scan_final<<<dim3(SCAN_NBLK), dim3(256), 0, stream>>>(cnt, bsum, off);

    // ...then features...
    proj_kernel<<<dim3((N_NODES + 63) / 64), dim3(256), 0, stream>>>(
        q, k, v, Wq, bq, Wk, bk, Wv, bv, xq, xk, xv);

    // ...then the edge MLP writing records straight to CSR slots.
    edge_weights<<<dim3(E_EDGES / (32 * EW_EPT)), dim3(256), 0, stream>>>(
        eidx, edges, Wp, bp, W1, b1, W2, b2, xq, xk, cnt, reccsr);

    node_accum<<<dim3(N_NODES / 16), dim3(256), 0, stream>>>(
        off, reccsr, xv, out);
}

// Round 17
// 164.988 us; speedup vs baseline: 1.2802x; 1.0415x over previous
//
#include <hip/hip_runtime.h>
#include <hip/hip_fp16.h>

#define N_NODES 50000
#define E_EDGES 800000
#define SCAN_TILE 1024
#define SCAN_NBLK ((N_NODES + SCAN_TILE - 1) / SCAN_TILE)   // 49
#define EW_EPT 8    // edges per octet per wave-iteration (8 independent chains)

__device__ __forceinline__ float sgpr_f(float x) {
    return __uint_as_float(__builtin_amdgcn_readfirstlane(__float_as_uint(x)));
}

#if defined(__has_builtin)
#if __has_builtin(__builtin_amdgcn_fdot2)
#define HAS_FDOT2 1
#endif
#endif

typedef _Float16 v2h_t __attribute__((ext_vector_type(2)));

__device__ __forceinline__ float fdot2f(__half2 a, __half2 b, float c) {
#ifdef HAS_FDOT2
    return __builtin_amdgcn_fdot2(*reinterpret_cast<v2h_t*>(&a),
                                  *reinterpret_cast<v2h_t*>(&b), c, false);
#else
    const float2 fa = __half22float2(a);
    const float2 fb = __half22float2(b);
    return fmaf(fa.x, fb.x, fmaf(fa.y, fb.y, c));
#endif
}

// packed relu: v_pk_max_f16 with inline constant 0
__device__ __forceinline__ __half2 relu_h2(__half2 x) {
    union { __half2 h; unsigned u; } a, r;
    a.h = x;
    asm("v_pk_max_f16 %0, %1, 0" : "=v"(r.u) : "v"(a.u));
    return r.h;
}

// DPP cross-lane moves (VALU pipe, no LDS).
// 0xB1 = quad_perm lane^1, 0x4E = quad_perm lane^2,
// 0x141 = ROW_HALF_MIRROR (lane i <-> 7-i within aligned 8-lane groups).
template <int CTRL>
__device__ __forceinline__ float dpp_mov_f32(float x) {
    return __int_as_float(__builtin_amdgcn_update_dpp(
        0, __float_as_int(x), CTRL, 0xF, 0xF, true));
}
template <int CTRL>
__device__ __forceinline__ int dpp_mov_i32(int x) {
    return __builtin_amdgcn_update_dpp(0, x, CTRL, 0xF, 0xF, true);
}
// full 8-lane (octet) all-reduce (validated r11)
__device__ __forceinline__ float oct_sum(float x) {
    x += dpp_mov_f32<0xB1>(x);
    x += dpp_mov_f32<0x4E>(x);
    x += dpp_mov_f32<0x141>(x);
    return x;
}

// ---------------------------------------------------------------------------
// Projection kernel, fp16-dot2 version (r16-proven): W staged in LDS as half2
// k-pairs (24 KB), inputs converted to half2, fdot2 with f32 accumulate.
// ---------------------------------------------------------------------------
__global__ __launch_bounds__(256) void proj_kernel(
    const float* __restrict__ qin, const float* __restrict__ kin, const float* __restrict__ vin,
    const float* __restrict__ Wq, const float* __restrict__ bq,
    const float* __restrict__ Wk, const float* __restrict__ bk,
    const float* __restrict__ Wv, const float* __restrict__ bv,
    __half* __restrict__ xq, __half* __restrict__ xk, __half* __restrict__ xv)
{
    // Wh[m][kp][c]: half2 {W[2kp][c], W[2kp+1][c]}, kp=0..31, c=0..63
    __shared__ unsigned Wh[3 * 2048];
    const int tid = threadIdx.x;
    #pragma unroll
    for (int it = 0; it < 8; ++it) {
        const int idx = it * 256 + tid;          // 0..2047
        const int kp = idx >> 6, c = idx & 63;
        {
            const __half2 h = __floats2half2_rn(Wq[(2 * kp) * 64 + c], Wq[(2 * kp + 1) * 64 + c]);
            Wh[idx] = *reinterpret_cast<const unsigned*>(&h);
        }
        {
            const __half2 h = __floats2half2_rn(Wk[(2 * kp) * 64 + c], Wk[(2 * kp + 1) * 64 + c]);
            Wh[2048 + idx] = *reinterpret_cast<const unsigned*>(&h);
        }
        {
            const __half2 h = __floats2half2_rn(Wv[(2 * kp) * 64 + c], Wv[(2 * kp + 1) * 64 + c]);
            Wh[4096 + idx] = *reinterpret_cast<const unsigned*>(&h);
        }
    }
    __syncthreads();

    const int cg = tid & 15;
    const int rg = tid >> 4;
    const int c0 = cg * 4;
    const int base = blockIdx.x * 64 + rg * 4;

    const float* ins[3]  = {qin, kin, vin};
    const float* bs[3]   = {bq, bk, bv};
    __half*      outs[3] = {xq, xk, xv};

    int rowi[4];
    #pragma unroll
    for (int rr = 0; rr < 4; ++rr)
        rowi[rr] = (base + rr < N_NODES) ? (base + rr) : (N_NODES - 1);

    #pragma unroll
    for (int m = 0; m < 3; ++m) {
        const float* in = ins[m];
        float4 acc[4];
        const float4 b4 = *reinterpret_cast<const float4*>(&bs[m][c0]);
        #pragma unroll
        for (int rr = 0; rr < 4; ++rr) acc[rr] = b4;

        for (int kk = 0; kk < 64; kk += 4) {
            __half2 xp[4][2];
            #pragma unroll
            for (int rr = 0; rr < 4; ++rr) {
                const float4 rv = *reinterpret_cast<const float4*>(&in[rowi[rr] * 64 + kk]);
                xp[rr][0] = __floats2half2_rn(rv.x, rv.y);
                xp[rr][1] = __floats2half2_rn(rv.z, rv.w);
            }
            #pragma unroll
            for (int h = 0; h < 2; ++h) {
                const int kp = (kk >> 1) + h;
                const uint4 wq = *reinterpret_cast<const uint4*>(&Wh[m * 2048 + kp * 64 + c0]);
                const __half2 w0 = *reinterpret_cast<const __half2*>(&wq.x);
                const __half2 w1 = *reinterpret_cast<const __half2*>(&wq.y);
                const __half2 w2 = *reinterpret_cast<const __half2*>(&wq.z);
                const __half2 w3 = *reinterpret_cast<const __half2*>(&wq.w);
                #pragma unroll
                for (int rr = 0; rr < 4; ++rr) {
                    acc[rr].x = fdot2f(xp[rr][h], w0, acc[rr].x);
                    acc[rr].y = fdot2f(xp[rr][h], w1, acc[rr].y);
                    acc[rr].z = fdot2f(xp[rr][h], w2, acc[rr].z);
                    acc[rr].w = fdot2f(xp[rr][h], w3, acc[rr].w);
                }
            }
        }
        #pragma unroll
        for (int rr = 0; rr < 4; ++rr) {
            if (base + rr < N_NODES) {
                union { __half2 h[2]; uint2 u; } pk;
                pk.h[0] = __floats2half2_rn(acc[rr].x, acc[rr].y);
                pk.h[1] = __floats2half2_rn(acc[rr].z, acc[rr].w);
                *reinterpret_cast<uint2*>(&outs[m][(size_t)(base + rr) * 64 + c0]) = pk.u;
            }
        }
    }
}

// ---------------------------------------------------------------------------
// Hierarchical scan, step A: per-1024-element block sums (49 blocks).
// ---------------------------------------------------------------------------
__global__ __launch_bounds__(256) void scan_sums(
    const int* __restrict__ cnt, int* __restrict__ bsum)
{
    const int tid  = threadIdx.x;
    const int base = blockIdx.x * SCAN_TILE + tid * 4;
    int s = 0;
    if (base + 3 < N_NODES) {
        const int4 t = *reinterpret_cast<const int4*>(&cnt[base]);
        s = t.x + t.y + t.z + t.w;
    } else {
        #pragma unroll
        for (int i = 0; i < 4; ++i)
            if (base + i < N_NODES) s += cnt[base + i];
    }
    #pragma unroll
    for (int d = 1; d < 64; d <<= 1) s += __shfl_xor(s, d);
    __shared__ int ws[4];
    if ((tid & 63) == 0) ws[tid >> 6] = s;
    __syncthreads();
    if (tid == 0) bsum[blockIdx.x] = ws[0] + ws[1] + ws[2] + ws[3];
}

// ---------------------------------------------------------------------------
// Hierarchical scan, step B: exclusive scan of the 49 block sums (one wave).
// ---------------------------------------------------------------------------
__global__ __launch_bounds__(64) void scan_bsum(int* __restrict__ bsum)
{
    const int lane = threadIdx.x;
    const int v = (lane < SCAN_NBLK) ? bsum[lane] : 0;
    int incl = v;
    #pragma unroll
    for (int d = 1; d < 64; d <<= 1) {
        const int t = __shfl_up(incl, d);
        if (lane >= d) incl += t;
    }
    if (lane < SCAN_NBLK) bsum[lane] = incl - v;
}

// ---------------------------------------------------------------------------
// Hierarchical scan, step C: local exclusive scan + block offset.
// Writes off[] and re-purposes cnt[] (in-place) as the scatter cursor.
// ---------------------------------------------------------------------------
__global__ __launch_bounds__(256) void scan_final(
    int* __restrict__ cnt, const int* __restrict__ bsum, int* __restrict__ off)
{
    const int tid  = threadIdx.x;
    const int base = blockIdx.x * SCAN_TILE + tid * 4;

    int v0 = 0, v1 = 0, v2 = 0, v3 = 0;
    if (base + 3 < N_NODES) {
        const int4 t = *reinterpret_cast<const int4*>(&cnt[base]);
        v0 = t.x; v1 = t.y; v2 = t.z; v3 = t.w;
    } else {
        if (base + 0 < N_NODES) v0 = cnt[base + 0];
        if (base + 1 < N_NODES) v1 = cnt[base + 1];
        if (base + 2 < N_NODES) v2 = cnt[base + 2];
        if (base + 3 < N_NODES) v3 = cnt[base + 3];
    }
    const int s = v0 + v1 + v2 + v3;

    int incl = s;
    #pragma unroll
    for (int d = 1; d < 64; d <<= 1) {
        const int t = __shfl_up(incl, d);
        if ((tid & 63) >= d) incl += t;
    }
    __shared__ int wsum[4];
    const int wave = tid >> 6;
    if ((tid & 63) == 63) wsum[wave] = incl;
    __syncthreads();
    int woff = 0;
    #pragma unroll
    for (int w = 0; w < 3; ++w)
        if (w < wave) woff += wsum[w];

    int run = bsum[blockIdx.x] + woff + (incl - s);
    if (base + 0 < N_NODES) { off[base + 0] = run; cnt[base + 0] = run; run += v0; }
    if (base + 1 < N_NODES) { off[base + 1] = run; cnt[base + 1] = run; run += v1; }
    if (base + 2 < N_NODES) { off[base + 2] = run; cnt[base + 2] = run; run += v2; }
    if (base + 3 < N_NODES) { off[base + 3] = run; cnt[base + 3] = run; run += v3; }

    if (blockIdx.x == 0 && tid == 0) off[N_NODES] = E_EDGES;
}

// ---------------------------------------------------------------------------
// Edge-weights kernel (r15-proven): coalesced edge-order record + histogram.
// Record: word0 = src | (dst<<16); word1 = w[0..3] u8; word2 = w[4..7] u8;
//         word3 = p (f32). Softmax without max-subtraction.
// ---------------------------------------------------------------------------
__global__ __launch_bounds__(256) void edge_weights(
    const int* __restrict__ eidx, const float* __restrict__ edges,
    const float* __restrict__ Wp, const float* __restrict__ bp,
    const float* __restrict__ W1, const float* __restrict__ b1,
    const float* __restrict__ W2, const float* __restrict__ b2,
    const __half* __restrict__ xq, const __half* __restrict__ xk,
    int* __restrict__ cnt, uint4* __restrict__ rece)
{
    const int tid  = threadIdx.x;
    const int lane = tid & 63;
    const int o    = lane >> 3;
    const int r    = lane & 7;
    const int wave = tid >> 6;

    __half2 W1h[4][8];
    #pragma unroll
    for (int i = 0; i < 4; ++i) {
        const float4 a0 = *reinterpret_cast<const float4*>(&W1[(8 * r + 2 * i) * 8]);
        const float4 a1 = *reinterpret_cast<const float4*>(&W1[(8 * r + 2 * i) * 8 + 4]);
        const float4 c0 = *reinterpret_cast<const float4*>(&W1[(8 * r + 2 * i + 1) * 8]);
        const float4 c1 = *reinterpret_cast<const float4*>(&W1[(8 * r + 2 * i + 1) * 8 + 4]);
        W1h[i][0] = __floats2half2_rn(a0.x, c0.x);
        W1h[i][1] = __floats2half2_rn(a0.y, c0.y);
        W1h[i][2] = __floats2half2_rn(a0.z, c0.z);
        W1h[i][3] = __floats2half2_rn(a0.w, c0.w);
        W1h[i][4] = __floats2half2_rn(a1.x, c1.x);
        W1h[i][5] = __floats2half2_rn(a1.y, c1.y);
        W1h[i][6] = __floats2half2_rn(a1.z, c1.z);
        W1h[i][7] = __floats2half2_rn(a1.w, c1.w);
    }
    float W2col[8];
    #pragma unroll
    for (int jj = 0; jj < 8; ++jj) W2col[jj] = W2[jj * 8 + r];
    float b1u[8];
    #pragma unroll
    for (int j = 0; j < 8; ++j) b1u[j] = sgpr_f(b1[j]);
    const float b2r = b2[r];
    const float wpA = Wp[2 * r], wpB = Wp[2 * r + 1];
    const float bp0 = sgpr_f(bp[0]);

    const int wb = (blockIdx.x * 4 + wave) * (8 * EW_EPT);

    #pragma unroll
    for (int t = 0; t < EW_EPT; ++t) {
        const int e = wb + t * 8 + o;

        const int2 sd = *reinterpret_cast<const int2*>(&eidx[2 * e]);
        const float2 e2 = *reinterpret_cast<const float2*>(&edges[(size_t)e * 16 + 2 * r]);

        uint4 q4u = *reinterpret_cast<const uint4*>(&xq[(size_t)sd.x * 64 + 8 * r]);
        uint4 k4u = *reinterpret_cast<const uint4*>(&xk[(size_t)sd.y * 64 + 8 * r]);

        float p = fmaf(e2.x, wpA, e2.y * wpB);
        p = oct_sum(p) + bp0;

        const __half2 p2 = __float2half2_rn(p);
        const __half2* qh = reinterpret_cast<const __half2*>(&q4u);
        const __half2* kh = reinterpret_cast<const __half2*>(&k4u);

        float part[8];
        #pragma unroll
        for (int jj = 0; jj < 8; ++jj) part[jj] = 0.f;
        #pragma unroll
        for (int i = 0; i < 4; ++i) {
            const __half2 d = relu_h2(__hadd2(__hsub2(kh[i], qh[i]), p2));
            #pragma unroll
            for (int jj = 0; jj < 8; ++jj)
                part[jj] = fdot2f(d, W1h[i][jj], part[jj]);
        }
        #pragma unroll
        for (int jj = 0; jj < 8; ++jj) part[jj] = oct_sum(part[jj]);

        float h2 = b2r;
        #pragma unroll
        for (int jj = 0; jj < 8; ++jj) {
            const float h1 = fmaxf(part[jj] + b1u[jj], 0.f);
            h2 = fmaf(h1, W2col[jj], h2);
        }

        // softmax without max-subtraction (|h2| << 88, f32-exp safe)
        const float ex = __expf(h2);
        const float sm = oct_sum(ex);
        const float w  = ex / sm;

        // quantize to u8 (*255, deferred 1/255 in node_accum's epilogue)
        const unsigned wu = (unsigned)__float2uint_rn(w * 255.f);
        unsigned word = wu << (8 * (r & 3));
        word |= (unsigned)dpp_mov_i32<0xB1>((int)word);   // quad or-combine
        word |= (unsigned)dpp_mov_i32<0x4E>((int)word);
        const unsigned other = (unsigned)dpp_mov_i32<0x141>((int)word); // other quad's word

        if (r == 0) {
            uint4 rec;
            rec.x = (unsigned)sd.x | ((unsigned)sd.y << 16);
            rec.y = word;    // w[0..3]
            rec.z = other;   // w[4..7]
            rec.w = __float_as_uint(p);
            rece[e] = rec;   // coalesced: 8 octets -> 128B contiguous
        }
        if (r == 1) atomicAdd(&cnt[sd.x], 1);
    }
}

// ---------------------------------------------------------------------------
// Scatter: ONE random 16B store per edge. src comes from the record.
// ---------------------------------------------------------------------------
__global__ __launch_bounds__(256) void scatter_kernel(
    const uint4* __restrict__ rece, int* __restrict__ cursor,
    uint4* __restrict__ reccsr)
{
    const int e = blockIdx.x * 256 + threadIdx.x;
    const uint4 rec = rece[e];
    const int src = (int)(rec.x & 0xFFFFu);
    const int pos = atomicAdd(&cursor[src], 1);
    reccsr[pos] = rec;
}

// ---------------------------------------------------------------------------
// Node accumulation (r14-proven): 16 lanes per node (2 sub-octets, alternate
// edges). Lane r owns channels 8r..8r+7; weights u8 with deferred 1/255.
// ---------------------------------------------------------------------------
__global__ __launch_bounds__(256) void node_accum(
    const int* __restrict__ off, const uint4* __restrict__ reccsr,
    const __half* __restrict__ xv, float* __restrict__ out)
{
    const int tid  = threadIdx.x;
    const int lane = tid & 63;
    const int grp  = lane >> 4;
    const int sub  = (lane >> 3) & 1;
    const int r    = lane & 7;
    const int wave = tid >> 6;

    const int node = blockIdx.x * 16 + wave * 4 + grp;

    const int beg = off[node];
    const int end = off[node + 1];

    float acc[8];
    #pragma unroll
    for (int i = 0; i < 8; ++i) acc[i] = 0.f;

    int j = beg + sub;
    uint4 rec;
    if (j < end) rec = reccsr[j];

    for (; j < end; j += 2) {
        const uint4 cur = rec;
        const int   dst = (int)(cur.x >> 16);
        const float p   = __uint_as_float(cur.w);

        union { uint4 u; __half2 h[4]; } v4;
        v4.u = *reinterpret_cast<const uint4*>(&xv[(size_t)dst * 64 + 8 * r]);

        if (j + 2 < end) rec = reccsr[j + 2];

        float wf[8];
        #pragma unroll
        for (int i = 0; i < 4; ++i) {
            wf[i]     = (float)((cur.y >> (8 * i)) & 255u);
            wf[4 + i] = (float)((cur.z >> (8 * i)) & 255u);
        }

        #pragma unroll
        for (int i = 0; i < 4; ++i) {
            const float2 fv = __half22float2(v4.h[i]);
            acc[2 * i]     = fmaf(fv.x + p, wf[2 * i],     acc[2 * i]);
            acc[2 * i + 1] = fmaf(fv.y + p, wf[2 * i + 1], acc[2 * i + 1]);
        }
    }

    #pragma unroll
    for (int i = 0; i < 8; ++i)
        acc[i] += __shfl_xor(acc[i], 8);

    if (sub == 0) {
        const float c = 1.f / 255.f;
        float* orow = &out[(size_t)node * 64 + 8 * r];
        *reinterpret_cast<float4*>(orow) =
            make_float4(acc[0] * c, acc[1] * c, acc[2] * c, acc[3] * c);
        *reinterpret_cast<float4*>(orow + 4) =
            make_float4(acc[4] * c, acc[5] * c, acc[6] * c, acc[7] * c);
    }
}

extern "C" void kernel_launch(void* const* d_in, const int* in_sizes, int n_in,
                              void* d_out, int out_size, void* d_ws, size_t ws_size,
                              hipStream_t stream) {
    const float* q     = (const float*)d_in[0];
    const float* k     = (const float*)d_in[1];
    const float* v     = (const float*)d_in[2];
    const float* edges = (const float*)d_in[3];
    const int*   eidx  = (const int*)d_in[4];
    const float* Wq    = (const float*)d_in[5];
    const float* bq    = (const float*)d_in[6];
    const float* Wk    = (const float*)d_in[7];
    const float* bk    = (const float*)d_in[8];
    const float* Wv    = (const float*)d_in[9];
    const float* bv    = (const float*)d_in[10];
    const float* Wp    = (const float*)d_in[11];
    const float* bp    = (const float*)d_in[12];
    const float* W1    = (const float*)d_in[13];
    const float* b1    = (const float*)d_in[14];
    const float* W2    = (const float*)d_in[15];
    const float* b2    = (const float*)d_in[16];
    float* out = (float*)d_out;

    // workspace layout
    char* ws = (char*)d_ws;
    __half* xq = (__half*)ws;          ws += (size_t)N_NODES * 64 * sizeof(__half);
    __half* xk = (__half*)ws;          ws += (size_t)N_NODES * 64 * sizeof(__half);
    __half* xv = (__half*)ws;          ws += (size_t)N_NODES * 64 * sizeof(__half);
    int* cnt  = (int*)ws;              ws += (size_t)(N_NODES + 64) * sizeof(int);
    int* off  = (int*)ws;              ws += (size_t)(N_NODES + 64) * sizeof(int);
    int* bsum = (int*)ws;              ws += (size_t)64 * sizeof(int);
    uint4* rece   = (uint4*)ws;        ws += (size_t)E_EDGES * sizeof(uint4);   // 12.8 MB
    uint4* reccsr = (uint4*)ws;        ws += (size_t)E_EDGES * sizeof(uint4);   // 12.8 MB

    hipMemsetAsync(cnt, 0, (size_t)N_NODES * sizeof(int), stream);

    proj_kernel<<<dim3((N_NODES + 63) / 64), dim3(256), 0, stream>>>(
        q, k, v, Wq, bq, Wk, bk, Wv, bv, xq, xk, xv);

    edge_weights<<<dim3(E_EDGES / (32 * EW_EPT)), dim3(256), 0, stream>>>(
        eidx, edges, Wp, bp, W1, b1, W2, b2, xq, xk, cnt, rece);

    scan_sums<<<dim3(SCAN_NBLK), dim3(256), 0, stream>>>(cnt, bsum);
    scan_bsum<<<dim3(1), dim3(64), 0, stream>>>(bsum);
    scan_final<<<dim3(SCAN_NBLK), dim3(256), 0, stream>>>(cnt, bsum, off);

    scatter_kernel<<<dim3(E_EDGES / 256), dim3(256), 0, stream>>>(
        rece, cnt, reccsr);

    node_accum<<<dim3(N_NODES / 16), dim3(256), 0, stream>>>(
        off, reccsr, xv, out);
}